// Round 2
// baseline (2399.795 us; speedup 1.0000x reference)
//
#include <hip/hip_runtime.h>
#include <hip/hip_bf16.h>
#include <cstddef>

// B=8, L=512, H=768, DIN=1536, N=64, R=48, Kc=4. M = B*L = 4096.
#define DIN 1536
#define LSEQ 512

__device__ inline float readlane_f(float v, int l) {
  return __uint_as_float(__builtin_amdgcn_readlane(__float_as_uint(v), l));
}

// Templated fp32 GEMM. 256 threads. TBK=16 fixed.
// AMODE 0: A[row*lda + k]
// AMODE 1: A = concat(text,audio,video) along k (segments of 768; BK tiles never straddle)
// AMODE 2: A[row][k] = A0[((row>>9)*DIN + k)*LSEQ + (row&511)]  (transposed [B][DIN][L])
// EPI 0: C=acc   1: +bias[col]   3: +resid[row*ldc+col]
// EPI 4: softplus(acc+bias[col]) stored transposed [b][col][l]
// EPI 5: split: col<1536 -> C[row*1536+col]; col>=1536 -> C2[b][col-1536][l] transposed
template<int TBM, int TBN, int TM, int TN, int AMODE, int EPI>
__global__ __launch_bounds__(256) void gemm_t(
    const float* __restrict__ A0, const float* __restrict__ A1, const float* __restrict__ A2,
    const float* __restrict__ Bmat, const float* __restrict__ bias,
    const float* __restrict__ resid, float* __restrict__ C, float* __restrict__ C2,
    int M, int N, int K, int lda, int ldc)
{
  constexpr int TBK = 16;
  __shared__ float As[TBK][TBM + 4];
  __shared__ float Bs[TBK][TBN + 4];
  constexpr int NTX = TBN / TN;
  constexpr int NTY = TBM / TM;
  static_assert(NTX * NTY == 256, "");
  const int tid = threadIdx.x;
  const int bm = blockIdx.x * TBM, bn = blockIdx.y * TBN;
  const int tx = tid % NTX, ty = tid / NTX;
  float acc[TM][TN] = {};

  for (int k0 = 0; k0 < K; k0 += TBK) {
    if (AMODE == 0) {
      #pragma unroll
      for (int e = tid; e < TBM * TBK; e += 256) {
        int m = e >> 4, kk = e & 15;
        As[kk][m] = A0[(size_t)(bm + m) * lda + k0 + kk];
      }
    } else if (AMODE == 1) {
      int seg = k0 / 768;
      const float* Ag = (seg == 0) ? A0 : (seg == 1) ? A1 : A2;
      int kb = k0 - seg * 768;
      #pragma unroll
      for (int e = tid; e < TBM * TBK; e += 256) {
        int m = e >> 4, kk = e & 15;
        As[kk][m] = Ag[(size_t)(bm + m) * 768 + kb + kk];
      }
    } else {
      #pragma unroll
      for (int e = tid; e < TBM * TBK; e += 256) {
        int kk = e / TBM, m = e - kk * TBM;
        int row = bm + m;
        As[kk][m] = A0[((size_t)(row >> 9) * DIN + k0 + kk) * LSEQ + (row & 511)];
      }
    }
    #pragma unroll
    for (int e = tid; e < TBK * TBN; e += 256) {
      int kk = e / TBN, n = e - kk * TBN;
      int col = bn + n;
      Bs[kk][n] = (col < N) ? Bmat[(size_t)(k0 + kk) * N + col] : 0.f;
    }
    __syncthreads();
    #pragma unroll
    for (int kk = 0; kk < TBK; ++kk) {
      float a[TM], b[TN];
      #pragma unroll
      for (int i = 0; i < TM / 4; ++i) {
        float4 v = *reinterpret_cast<const float4*>(&As[kk][ty * TM + i * 4]);
        a[i*4] = v.x; a[i*4+1] = v.y; a[i*4+2] = v.z; a[i*4+3] = v.w;
      }
      #pragma unroll
      for (int j = 0; j < TN / 4; ++j) {
        float4 v = *reinterpret_cast<const float4*>(&Bs[kk][tx * TN + j * 4]);
        b[j*4] = v.x; b[j*4+1] = v.y; b[j*4+2] = v.z; b[j*4+3] = v.w;
      }
      #pragma unroll
      for (int i = 0; i < TM; ++i)
        #pragma unroll
        for (int j = 0; j < TN; ++j)
          acc[i][j] = fmaf(a[i], b[j], acc[i][j]);
    }
    __syncthreads();
  }

  if (EPI == 0 || EPI == 1 || EPI == 3) {
    #pragma unroll
    for (int i = 0; i < TM; ++i) {
      int row = bm + ty * TM + i;
      #pragma unroll
      for (int j0 = 0; j0 < TN; j0 += 4) {
        int col = bn + tx * TN + j0;
        if (col < N) {  // all N are multiples of 4; group all-or-none
          float4 v;
          v.x = acc[i][j0]; v.y = acc[i][j0+1]; v.z = acc[i][j0+2]; v.w = acc[i][j0+3];
          if (EPI == 1) { v.x += bias[col]; v.y += bias[col+1]; v.z += bias[col+2]; v.w += bias[col+3]; }
          if (EPI == 3) {
            const float4 r = *reinterpret_cast<const float4*>(&resid[(size_t)row * ldc + col]);
            v.x += r.x; v.y += r.y; v.z += r.z; v.w += r.w;
          }
          *reinterpret_cast<float4*>(&C[(size_t)row * ldc + col]) = v;
        }
      }
    }
  } else if (EPI == 4) {
    // softplus(acc+bias) -> transposed [b][col][l]; all TM rows share b
    int l0 = bm + ty * TM;
    int b = l0 >> 9, lo = l0 & 511;
    #pragma unroll
    for (int j = 0; j < TN; ++j) {
      int col = bn + tx * TN + j;
      float bj = bias[col];
      float* base = C + ((size_t)b * DIN + col) * LSEQ + lo;
      #pragma unroll
      for (int i0 = 0; i0 < TM; i0 += 4) {
        float4 v;
        float t0 = acc[i0+0][j] + bj, t1 = acc[i0+1][j] + bj;
        float t2 = acc[i0+2][j] + bj, t3 = acc[i0+3][j] + bj;
        v.x = fmaxf(t0, 0.f) + log1pf(__expf(-fabsf(t0)));
        v.y = fmaxf(t1, 0.f) + log1pf(__expf(-fabsf(t1)));
        v.z = fmaxf(t2, 0.f) + log1pf(__expf(-fabsf(t2)));
        v.w = fmaxf(t3, 0.f) + log1pf(__expf(-fabsf(t3)));
        *reinterpret_cast<float4*>(base + i0) = v;
      }
    }
  } else if (EPI == 5) {
    if (bn < 1536) {
      #pragma unroll
      for (int i = 0; i < TM; ++i) {
        int row = bm + ty * TM + i;
        #pragma unroll
        for (int j0 = 0; j0 < TN; j0 += 4) {
          int col = bn + tx * TN + j0;
          float4 v;
          v.x = acc[i][j0]; v.y = acc[i][j0+1]; v.z = acc[i][j0+2]; v.w = acc[i][j0+3];
          *reinterpret_cast<float4*>(&C[(size_t)row * 1536 + col]) = v;
        }
      }
    } else {
      int l0 = bm + ty * TM;
      int b = l0 >> 9, lo = l0 & 511;
      #pragma unroll
      for (int j = 0; j < TN; ++j) {
        int col = bn - 1536 + tx * TN + j;
        float* base = C2 + ((size_t)b * DIN + col) * LSEQ + lo;
        #pragma unroll
        for (int i0 = 0; i0 < TM; i0 += 4) {
          float4 v;
          v.x = acc[i0+0][j]; v.y = acc[i0+1][j]; v.z = acc[i0+2][j]; v.w = acc[i0+3][j];
          *reinterpret_cast<float4*>(base + i0) = v;
        }
      }
    }
  }
}

__device__ inline float block_sum256(float s, float* red) {
  #pragma unroll
  for (int o = 32; o > 0; o >>= 1) s += __shfl_xor(s, o, 64);
  int tid = threadIdx.x;
  __syncthreads();
  if ((tid & 63) == 0) red[tid >> 6] = s;
  __syncthreads();
  return red[0] + red[1] + red[2] + red[3];
}

// fused = LN1(pre); h = LN2(fused)
__global__ __launch_bounds__(256) void ln2_k(
    const float* __restrict__ pre,
    const float* __restrict__ g1, const float* __restrict__ b1,
    const float* __restrict__ g2, const float* __restrict__ b2,
    float* __restrict__ fused, float* __restrict__ hout)
{
  __shared__ float red[4];
  const int row = blockIdx.x;
  const int tid = threadIdx.x;
  const float* x = pre + (size_t)row * 768;
  float v0 = x[tid], v1 = x[tid + 256], v2 = x[tid + 512];

  float mu = block_sum256(v0 + v1 + v2, red) * (1.f / 768.f);
  float c0 = v0 - mu, c1 = v1 - mu, c2 = v2 - mu;
  float var = block_sum256(c0*c0 + c1*c1 + c2*c2, red) * (1.f / 768.f);
  float r = rsqrtf(var + 1e-5f);
  float f0 = c0 * r * g1[tid] + b1[tid];
  float f1 = c1 * r * g1[tid + 256] + b1[tid + 256];
  float f2 = c2 * r * g1[tid + 512] + b1[tid + 512];
  float* fo = fused + (size_t)row * 768;
  fo[tid] = f0; fo[tid + 256] = f1; fo[tid + 512] = f2;

  float mu2 = block_sum256(f0 + f1 + f2, red) * (1.f / 768.f);
  float d0 = f0 - mu2, d1 = f1 - mu2, d2 = f2 - mu2;
  float var2 = block_sum256(d0*d0 + d1*d1 + d2*d2, red) * (1.f / 768.f);
  float r2 = rsqrtf(var2 + 1e-5f);
  float* ho = hout + (size_t)row * 768;
  ho[tid]       = d0 * r2 * g2[tid] + b2[tid];
  ho[tid + 256] = d1 * r2 * g2[tid + 256] + b2[tid + 256];
  ho[tid + 512] = d2 * r2 * g2[tid + 512] + b2[tid + 512];
}

// Causal depthwise conv (K=4) + bias + silu, LDS-tiled.
// Reads x [4096][1536]; writes xct transposed [B][DIN][L].
__global__ __launch_bounds__(256) void conv2_k(
    const float* __restrict__ xbuf, const float* __restrict__ w,
    const float* __restrict__ cb, float* __restrict__ xct)
{
  __shared__ float Xs[67][65];  // rows l0-3 .. l0+63, +1 pad breaks stride-64 conflicts
  const int tid = threadIdx.x;
  const int l0 = blockIdx.x * 64;
  const int d0 = blockIdx.y * 64;
  const int b  = blockIdx.z;
  for (int e = tid; e < 67 * 64; e += 256) {
    int r = e >> 6, dd = e & 63;
    int l = l0 - 3 + r;
    Xs[r][dd] = (l >= 0) ? xbuf[((size_t)b * 512 + l) * DIN + d0 + dd] : 0.f;
  }
  __syncthreads();
  const int lane = tid & 63, grp = tid >> 6;
  #pragma unroll
  for (int i = 0; i < 16; ++i) {
    int dd = grp + i * 4;
    int d = d0 + dd;
    float acc = cb[d];
    #pragma unroll
    for (int k = 0; k < 4; ++k)
      acc = fmaf(Xs[lane + k][dd], w[d * 4 + k], acc);
    xct[((size_t)b * DIN + d) * LSEQ + l0 + lane] = acc / (1.f + __expf(-acc));
  }
}

// Selective scan v2. Block = 4 waves sharing one b; wave -> d; lane -> state n.
// All per-(b,d) streams transposed [B][DIN][L]; B/C rows staged in LDS per block.
__global__ __launch_bounds__(256) void scan2_k(
    const float* __restrict__ delta_t, const float* __restrict__ xct,
    const float* __restrict__ dbl, const float* __restrict__ zt,
    const float* __restrict__ A_log, const float* __restrict__ Dv,
    float* __restrict__ ys)
{
  __shared__ float Bc[64][64];
  __shared__ float Cc[64][64];
  const int tid = threadIdx.x;
  const int lane = tid & 63;
  const int wv = tid >> 6;
  const int bid = blockIdx.x;          // 3072 = 8 * 384
  const int b = bid / 384;
  const int d = (bid - b * 384) * 4 + wv;
  const float Ad = -__expf(A_log[d * 64 + lane]);
  const float Dd = Dv[d];
  const size_t strm = ((size_t)b * DIN + d) * LSEQ;
  float h = 0.f;

  for (int l0 = 0; l0 < LSEQ; l0 += 64) {
    __syncthreads();
    #pragma unroll
    for (int i = 0; i < 16; ++i) {
      int t = wv + i * 4;
      const float* src = dbl + (size_t)(b * LSEQ + l0 + t) * 176;
      Bc[t][lane] = src[48 + lane];
      Cc[t][lane] = src[112 + lane];
    }
    float dt_v = delta_t[strm + l0 + lane];
    float u_v  = xct[strm + l0 + lane];
    float z_v  = zt[strm + l0 + lane];
    float du_v = dt_v * u_v;
    __syncthreads();

    float psave = 0.f;
    #pragma unroll
    for (int t = 0; t < 64; ++t) {
      float dt = readlane_f(dt_v, t);   // SALU broadcast, frees LDS pipe
      float du = readlane_f(du_v, t);
      float e = __expf(dt * Ad);
      h = fmaf(e, h, du * Bc[t][lane]);
      float p = h * Cc[t][lane];
      #pragma unroll
      for (int o = 32; o > 0; o >>= 1) p += __shfl_xor(p, o, 64);
      if (t == lane) psave = p;
    }
    float yv = (psave + u_v * Dd) * (z_v / (1.f + __expf(-z_v)));
    ys[strm + l0 + lane] = yv;
  }
}

__global__ __launch_bounds__(256) void mean_k(const float* __restrict__ bufF,
                                              float* __restrict__ out)
{
  int hh = blockIdx.x * 256 + threadIdx.x;
  int b = blockIdx.y;
  float s = 0.f;
  for (int l = 0; l < 512; ++l) s += bufF[((size_t)(b * 512 + l)) * 768 + hh];
  out[b * 768 + hh] = s * (1.f / 512.f);
}

extern "C" void kernel_launch(void* const* d_in, const int* in_sizes, int n_in,
                              void* d_out, int out_size, void* d_ws, size_t ws_size,
                              hipStream_t stream)
{
  const float* text      = (const float*)d_in[0];
  const float* audio     = (const float*)d_in[1];
  const float* video     = (const float*)d_in[2];
  const float* proj_w    = (const float*)d_in[3];
  const float* proj_b    = (const float*)d_in[4];
  const float* proj_ln_g = (const float*)d_in[5];
  const float* proj_ln_b = (const float*)d_in[6];
  const float* blk_ln_g  = (const float*)d_in[7];
  const float* blk_ln_b  = (const float*)d_in[8];
  const float* in_proj_w = (const float*)d_in[9];
  const float* conv_w    = (const float*)d_in[10];
  const float* conv_b    = (const float*)d_in[11];
  const float* x_proj_w  = (const float*)d_in[12];
  const float* dt_proj_w = (const float*)d_in[13];
  const float* dt_proj_b = (const float*)d_in[14];
  const float* A_log     = (const float*)d_in[15];
  const float* Dv        = (const float*)d_in[16];
  const float* out_projw = (const float*)d_in[17];
  float* out = (float*)d_out;

  float* ws = (float*)d_ws;
  const size_t SZ768 = (size_t)4096 * 768;
  const size_t SZD   = (size_t)4096 * 1536;
  float* pre     = ws;                 // [4096,768] (reused as final bufF)
  float* fused   = pre + SZ768;        // [4096,768]
  float* hbuf    = fused + SZ768;      // [4096,768] (reused as dbl [4096,176])
  float* xbuf    = hbuf + SZ768;       // [4096,1536]
  float* zt      = xbuf + SZD;         // [8][1536][512]
  float* xct     = zt + SZD;           // [8][1536][512]
  float* delta_t = xct + SZD;          // [8][1536][512]
  float* yst     = delta_t + SZD;      // [8][1536][512]
  float* dbl     = hbuf;
  float* bufF    = pre;

  // 1) pre = concat(text,audio,video) @ proj_w + proj_b
  gemm_t<128, 64, 8, 4, 1, 1><<<dim3(32, 12), 256, 0, stream>>>(
      text, audio, video, proj_w, proj_b, nullptr, pre, nullptr,
      4096, 768, 2304, 768, 768);
  // 2) fused = LN1(pre); h = LN2(fused)
  ln2_k<<<4096, 256, 0, stream>>>(pre, proj_ln_g, proj_ln_b, blk_ln_g, blk_ln_b, fused, hbuf);
  // 3) [x | z] = h @ in_proj_w; x -> xbuf [4096][1536], z -> zt transposed
  gemm_t<128, 128, 8, 8, 0, 5><<<dim3(32, 24), 256, 0, stream>>>(
      hbuf, nullptr, nullptr, in_proj_w, nullptr, nullptr, xbuf, zt,
      4096, 3072, 768, 768, 1536);
  // 4) xct = silu(causal_dwconv(x) + conv_b), transposed [B][DIN][L]
  conv2_k<<<dim3(8, 24, 8), 256, 0, stream>>>(xbuf, conv_w, conv_b, xct);
  // 5) dbl = xconv @ x_proj_w  [4096,176]  (A read transposed via AMODE 2)
  gemm_t<64, 64, 4, 4, 2, 0><<<dim3(64, 3), 256, 0, stream>>>(
      xct, nullptr, nullptr, x_proj_w, nullptr, nullptr, dbl, nullptr,
      4096, 176, 1536, 0, 176);
  // 6) delta_t = softplus(dbl[:, :48] @ dt_proj_w + dt_proj_b), transposed
  gemm_t<128, 128, 8, 8, 0, 4><<<dim3(32, 12), 256, 0, stream>>>(
      dbl, nullptr, nullptr, dt_proj_w, dt_proj_b, nullptr, delta_t, nullptr,
      4096, 1536, 48, 176, 0);
  // 7) selective scan -> yst transposed [B][DIN][L]
  scan2_k<<<3072, 256, 0, stream>>>(delta_t, xct, dbl, zt, A_log, Dv, yst);
  // 8) bufF = ys @ out_proj_w + fused
  gemm_t<128, 64, 8, 4, 2, 3><<<dim3(32, 12), 256, 0, stream>>>(
      yst, nullptr, nullptr, out_projw, nullptr, fused, bufF, nullptr,
      4096, 768, 1536, 0, 768);
  // 9) out = mean over L
  mean_k<<<dim3(3, 8), 256, 0, stream>>>(bufF, out);
}

// Round 3
// 1024.553 us; speedup vs baseline: 2.3423x; 2.3423x over previous
//
#include <hip/hip_runtime.h>
#include <hip/hip_bf16.h>
#include <cstddef>
#include <cstdint>

// B=8, L=512, H=768, DIN=1536, N=64, R=48, Kc=4. M = B*L = 4096.
#define DIN 1536
#define LSEQ 512

typedef __hip_bfloat16 bf16;
typedef __attribute__((ext_vector_type(8))) short short8x;
typedef __attribute__((ext_vector_type(4))) float f32x4;
typedef const __attribute__((address_space(1))) unsigned int* gp1;
typedef __attribute__((address_space(3))) unsigned int* lp3;

__device__ inline float readlane_f(float v, int l) {
  return __uint_as_float(__builtin_amdgcn_readlane(__float_as_uint(v), l));
}
__device__ inline void gload_lds(const bf16* g, unsigned short* l) {
  __builtin_amdgcn_global_load_lds((gp1)g, (lp3)l, 16, 0, 0);
}
__device__ inline void bsplit(float v, bf16& h, bf16& l) {
  h = __float2bfloat16(v);
  l = __float2bfloat16(v - __bfloat162float(h));
}
__device__ inline float softplusf(float t) {
  return fmaxf(t, 0.f) + log1pf(__expf(-fabsf(t)));
}

// ---------------------------------------------------------------------------
// bf16x3 MFMA GEMM. C = A*B fp32-accurate via hi/lo bf16 split (3 MFMA passes).
// A: [M][K] bf16 hi/lo (AMODE 1: concat of 3 segments of 768 along k).
// B: [N][K] bf16 hi/lo (transposed weights).
// LDS layout: [rows][32] bf16, k-chunks (8 bf16) XOR-swizzled by (row>>1)&3 to
// kill ds_read_b128 bank conflicts while keeping global_load_lds lane-contiguous.
// EPI 0: C=acc (ldc)        1: +bias[col]        3: +resid[row*ldc+col]
// EPI 4: softplus(acc+bias[col]) -> transposed [b][col][l]
// EPI 5: col<1536 -> C[row*ldc+col]; else acc -> C2 transposed [b][col-1536][l]
// ---------------------------------------------------------------------------
template<int TBM, int TBN, int WR, int WC, int AMODE, int EPI>
__global__ __launch_bounds__(256) void mgemm(
    const bf16* __restrict__ Ah0, const bf16* __restrict__ Al0,
    const bf16* __restrict__ Ah1, const bf16* __restrict__ Al1,
    const bf16* __restrict__ Ah2, const bf16* __restrict__ Al2,
    const bf16* __restrict__ Bh, const bf16* __restrict__ Bl,
    const float* __restrict__ bias, const float* __restrict__ resid,
    float* __restrict__ C, float* __restrict__ C2,
    int K, int lda, int ldc)
{
  constexpr int SM = TBM / WR, SN = TBN / WC;
  constexpr int T_M = SM / 16, T_N = SN / 16;
  __shared__ unsigned short sAh[TBM * 32], sAl[TBM * 32];
  __shared__ unsigned short sBh[TBN * 32], sBl[TBN * 32];
  const int tid = threadIdx.x;
  const int lane = tid & 63, wid = tid >> 6;
  const int bm = blockIdx.x * TBM, bn = blockIdx.y * TBN;
  const int wr = wid / WC, wc = wid % WC;

  // staging: chunk q = 16 rows; lane covers 8 bf16 at stored k-chunk (lane&3),
  // sourced from global k-chunk (lane&3)^((lane>>3)&3)  [row parity swizzle]
  const int stg_m = lane >> 2;
  const int stg_k = ((lane & 3) ^ ((lane >> 3) & 3)) * 8;
  // fragment read byte offset within a 16-row tile
  const int fo = (lane & 15) * 64 + ((((lane >> 4) ^ ((lane >> 1) & 3)) & 3) * 16);

  f32x4 acc[T_M][T_N];
  #pragma unroll
  for (int i = 0; i < T_M; ++i)
    #pragma unroll
    for (int j = 0; j < T_N; ++j) acc[i][j] = (f32x4){0.f, 0.f, 0.f, 0.f};

  for (int k0 = 0; k0 < K; k0 += 32) {
    __syncthreads();
    const bf16* pAh; const bf16* pAl; int ka;
    if (AMODE == 1) {
      int seg = k0 / 768;
      pAh = (seg == 0) ? Ah0 : (seg == 1) ? Ah1 : Ah2;
      pAl = (seg == 0) ? Al0 : (seg == 1) ? Al1 : Al2;
      ka = k0 - seg * 768;
    } else { pAh = Ah0; pAl = Al0; ka = k0; }
    #pragma unroll
    for (int it = 0; it < TBM / 64; ++it) {
      int q = it * 4 + wid;
      size_t go = (size_t)(bm + q * 16 + stg_m) * lda + ka + stg_k;
      gload_lds(pAh + go, &sAh[q * 512]);
      gload_lds(pAl + go, &sAl[q * 512]);
    }
    #pragma unroll
    for (int it = 0; it < TBN / 64; ++it) {
      int q = it * 4 + wid;
      size_t go = (size_t)(bn + q * 16 + stg_m) * K + k0 + stg_k;
      gload_lds(Bh + go, &sBh[q * 512]);
      gload_lds(Bl + go, &sBl[q * 512]);
    }
    __syncthreads();

    short8x ah[T_M], al[T_M], bh[T_N], bl[T_N];
    #pragma unroll
    for (int mi = 0; mi < T_M; ++mi) {
      int off = (wr * SM + mi * 16) * 64 + fo;
      ah[mi] = *(const short8x*)((const char*)sAh + off);
      al[mi] = *(const short8x*)((const char*)sAl + off);
    }
    #pragma unroll
    for (int nj = 0; nj < T_N; ++nj) {
      int off = (wc * SN + nj * 16) * 64 + fo;
      bh[nj] = *(const short8x*)((const char*)sBh + off);
      bl[nj] = *(const short8x*)((const char*)sBl + off);
    }
    #pragma unroll
    for (int mi = 0; mi < T_M; ++mi)
      #pragma unroll
      for (int nj = 0; nj < T_N; ++nj) {
        acc[mi][nj] = __builtin_amdgcn_mfma_f32_16x16x32_bf16(ah[mi], bh[nj], acc[mi][nj], 0, 0, 0);
        acc[mi][nj] = __builtin_amdgcn_mfma_f32_16x16x32_bf16(ah[mi], bl[nj], acc[mi][nj], 0, 0, 0);
        acc[mi][nj] = __builtin_amdgcn_mfma_f32_16x16x32_bf16(al[mi], bh[nj], acc[mi][nj], 0, 0, 0);
      }
  }

  // epilogue — C/D layout: col = lane&15, row = (lane>>4)*4 + reg
  const int cl = lane & 15, qd = lane >> 4;
  const int colbase = bn + wc * SN;
  const int rowbase = bm + wr * SM;
  if (EPI == 0 || EPI == 1 || EPI == 3) {
    #pragma unroll
    for (int mi = 0; mi < T_M; ++mi) {
      int r0 = rowbase + mi * 16 + qd * 4;
      #pragma unroll
      for (int nj = 0; nj < T_N; ++nj) {
        int col = colbase + nj * 16 + cl;
        float bv = (EPI == 1) ? bias[col] : 0.f;
        #pragma unroll
        for (int rg = 0; rg < 4; ++rg) {
          float v = acc[mi][nj][rg] + bv;
          if (EPI == 3) v += resid[(size_t)(r0 + rg) * ldc + col];
          C[(size_t)(r0 + rg) * ldc + col] = v;
        }
      }
    }
  } else if (EPI == 4) {
    #pragma unroll
    for (int mi = 0; mi < T_M; ++mi) {
      int m = rowbase + mi * 16 + qd * 4;
      int b = m >> 9, l = m & 511;
      #pragma unroll
      for (int nj = 0; nj < T_N; ++nj) {
        int col = colbase + nj * 16 + cl;
        float bv = bias[col];
        float4 v;
        v.x = softplusf(acc[mi][nj][0] + bv);
        v.y = softplusf(acc[mi][nj][1] + bv);
        v.z = softplusf(acc[mi][nj][2] + bv);
        v.w = softplusf(acc[mi][nj][3] + bv);
        *reinterpret_cast<float4*>(&C[((size_t)b * DIN + col) * LSEQ + l]) = v;
      }
    }
  } else if (EPI == 5) {
    if (bn < 1536) {
      #pragma unroll
      for (int mi = 0; mi < T_M; ++mi) {
        int r0 = rowbase + mi * 16 + qd * 4;
        #pragma unroll
        for (int nj = 0; nj < T_N; ++nj) {
          int col = colbase + nj * 16 + cl;
          #pragma unroll
          for (int rg = 0; rg < 4; ++rg)
            C[(size_t)(r0 + rg) * ldc + col] = acc[mi][nj][rg];
        }
      }
    } else {
      #pragma unroll
      for (int mi = 0; mi < T_M; ++mi) {
        int m = rowbase + mi * 16 + qd * 4;
        int b = m >> 9, l = m & 511;
        #pragma unroll
        for (int nj = 0; nj < T_N; ++nj) {
          int colz = colbase - 1536 + nj * 16 + cl;
          float4 v;
          v.x = acc[mi][nj][0]; v.y = acc[mi][nj][1];
          v.z = acc[mi][nj][2]; v.w = acc[mi][nj][3];
          *reinterpret_cast<float4*>(&C2[((size_t)b * DIN + colz) * LSEQ + l]) = v;
        }
      }
    }
  }
}

// ---------------------------------------------------------------------------
// Elementwise hi/lo split: src fp32 [rows][ldsrc] cols [0,Ws) -> [rows][Wd] (pad 0)
__global__ __launch_bounds__(256) void split_k(
    const float* __restrict__ src, bf16* __restrict__ hi, bf16* __restrict__ lo,
    int ldsrc, int Ws, int Wd, int total)
{
  int idx = blockIdx.x * 256 + threadIdx.x;
  if (idx >= total) return;
  int row = idx / Wd, c = idx - row * Wd;
  float v = (c < Ws) ? src[(size_t)row * ldsrc + c] : 0.f;
  bf16 h, l; bsplit(v, h, l);
  hi[idx] = h; lo[idx] = l;
}

// Transpose + split: dst[q][p] = src[p][q]; p in [P,Ppad) and q >= Q zero-filled.
// Grid covers (Ppad/64, Qpad/64, batch). dst leading dim = Ppad.
__global__ __launch_bounds__(256) void tsplit_k(
    const float* __restrict__ src, bf16* __restrict__ hi, bf16* __restrict__ lo,
    int P, int Q, int ldsrc, int Ppad, size_t sbs, size_t dbs)
{
  __shared__ float T[64][65];
  src += blockIdx.z * sbs; hi += blockIdx.z * dbs; lo += blockIdx.z * dbs;
  const int p0 = blockIdx.x * 64, q0 = blockIdx.y * 64;
  const int tid = threadIdx.x;
  {
    int j = tid & 63, i0 = tid >> 6;
    for (int i = i0; i < 64; i += 4) {
      int p = p0 + i, q = q0 + j;
      T[i][j] = (p < P && q < Q) ? src[(size_t)p * ldsrc + q] : 0.f;
    }
  }
  __syncthreads();
  {
    int ii = tid & 63, j0 = tid >> 6;
    for (int jj = j0; jj < 64; jj += 4) {
      bf16 h, l; bsplit(T[ii][jj], h, l);
      size_t o = (size_t)(q0 + jj) * Ppad + p0 + ii;
      hi[o] = h; lo[o] = l;
    }
  }
}

// ---------------------------------------------------------------------------
__device__ inline float block_sum256(float s, float* red) {
  #pragma unroll
  for (int o = 32; o > 0; o >>= 1) s += __shfl_xor(s, o, 64);
  int tid = threadIdx.x;
  __syncthreads();
  if ((tid & 63) == 0) red[tid >> 6] = s;
  __syncthreads();
  return red[0] + red[1] + red[2] + red[3];
}

// fused = LN1(pre); h = LN2(fused) written as bf16 hi/lo (GEMM-A operand)
__global__ __launch_bounds__(256) void ln2_k(
    const float* __restrict__ pre,
    const float* __restrict__ g1, const float* __restrict__ b1,
    const float* __restrict__ g2, const float* __restrict__ b2,
    float* __restrict__ fused, bf16* __restrict__ hAh, bf16* __restrict__ hAl)
{
  __shared__ float red[4];
  const int row = blockIdx.x;
  const int tid = threadIdx.x;
  const float* x = pre + (size_t)row * 768;
  float v0 = x[tid], v1 = x[tid + 256], v2 = x[tid + 512];

  float mu = block_sum256(v0 + v1 + v2, red) * (1.f / 768.f);
  float c0 = v0 - mu, c1 = v1 - mu, c2 = v2 - mu;
  float var = block_sum256(c0*c0 + c1*c1 + c2*c2, red) * (1.f / 768.f);
  float r = rsqrtf(var + 1e-5f);
  float f0 = c0 * r * g1[tid] + b1[tid];
  float f1 = c1 * r * g1[tid + 256] + b1[tid + 256];
  float f2 = c2 * r * g1[tid + 512] + b1[tid + 512];
  float* fo = fused + (size_t)row * 768;
  fo[tid] = f0; fo[tid + 256] = f1; fo[tid + 512] = f2;

  float mu2 = block_sum256(f0 + f1 + f2, red) * (1.f / 768.f);
  float d0 = f0 - mu2, d1 = f1 - mu2, d2 = f2 - mu2;
  float var2 = block_sum256(d0*d0 + d1*d1 + d2*d2, red) * (1.f / 768.f);
  float r2 = rsqrtf(var2 + 1e-5f);
  float h0 = d0 * r2 * g2[tid] + b2[tid];
  float h1 = d1 * r2 * g2[tid + 256] + b2[tid + 256];
  float h2 = d2 * r2 * g2[tid + 512] + b2[tid + 512];
  bf16 hh, hl;
  size_t o = (size_t)row * 768;
  bsplit(h0, hh, hl); hAh[o + tid] = hh; hAl[o + tid] = hl;
  bsplit(h1, hh, hl); hAh[o + tid + 256] = hh; hAl[o + tid + 256] = hl;
  bsplit(h2, hh, hl); hAh[o + tid + 512] = hh; hAl[o + tid + 512] = hl;
}

// Causal depthwise conv (K=4) + bias + silu; x [4096][1536] -> xct [B][DIN][L]
__global__ __launch_bounds__(256) void conv2_k(
    const float* __restrict__ xbuf, const float* __restrict__ w,
    const float* __restrict__ cb, float* __restrict__ xct)
{
  __shared__ float Xs[67][65];
  const int tid = threadIdx.x;
  const int l0 = blockIdx.x * 64;
  const int d0 = blockIdx.y * 64;
  const int b  = blockIdx.z;
  for (int e = tid; e < 67 * 64; e += 256) {
    int r = e >> 6, dd = e & 63;
    int l = l0 - 3 + r;
    Xs[r][dd] = (l >= 0) ? xbuf[((size_t)b * 512 + l) * DIN + d0 + dd] : 0.f;
  }
  __syncthreads();
  const int lane = tid & 63, grp = tid >> 6;
  #pragma unroll
  for (int i = 0; i < 16; ++i) {
    int dd = grp + i * 4;
    int d = d0 + dd;
    float acc = cb[d];
    #pragma unroll
    for (int k = 0; k < 4; ++k)
      acc = fmaf(Xs[lane + k][dd], w[d * 4 + k], acc);
    xct[((size_t)b * DIN + d) * LSEQ + l0 + lane] = acc / (1.f + __expf(-acc));
  }
}

// Selective scan: 4 waves/block share b; wave -> d; lane -> state n. dbl ld=192.
__global__ __launch_bounds__(256) void scan2_k(
    const float* __restrict__ delta_t, const float* __restrict__ xct,
    const float* __restrict__ dbl, const float* __restrict__ zt,
    const float* __restrict__ A_log, const float* __restrict__ Dv,
    float* __restrict__ ys)
{
  __shared__ float Bc[64][64];
  __shared__ float Cc[64][64];
  const int tid = threadIdx.x;
  const int lane = tid & 63;
  const int wv = tid >> 6;
  const int bid = blockIdx.x;          // 3072 = 8 * 384
  const int b = bid / 384;
  const int d = (bid - b * 384) * 4 + wv;
  const float Ad = -__expf(A_log[d * 64 + lane]);
  const float Dd = Dv[d];
  const size_t strm = ((size_t)b * DIN + d) * LSEQ;
  float h = 0.f;

  for (int l0 = 0; l0 < LSEQ; l0 += 64) {
    __syncthreads();
    #pragma unroll
    for (int i = 0; i < 16; ++i) {
      int t = wv + i * 4;
      const float* src = dbl + (size_t)(b * LSEQ + l0 + t) * 192;
      Bc[t][lane] = src[48 + lane];
      Cc[t][lane] = src[112 + lane];
    }
    float dt_v = delta_t[strm + l0 + lane];
    float u_v  = xct[strm + l0 + lane];
    float z_v  = zt[strm + l0 + lane];
    float du_v = dt_v * u_v;
    __syncthreads();

    float psave = 0.f;
    #pragma unroll
    for (int t = 0; t < 64; ++t) {
      float dt = readlane_f(dt_v, t);
      float du = readlane_f(du_v, t);
      float e = __expf(dt * Ad);
      h = fmaf(e, h, du * Bc[t][lane]);
      float p = h * Cc[t][lane];
      #pragma unroll
      for (int o = 32; o > 0; o >>= 1) p += __shfl_xor(p, o, 64);
      if (t == lane) psave = p;
    }
    float yv = (psave + u_v * Dd) * (z_v / (1.f + __expf(-z_v)));
    ys[strm + l0 + lane] = yv;
  }
}

__global__ __launch_bounds__(256) void mean_k(const float* __restrict__ bufF,
                                              float* __restrict__ out)
{
  int hh = blockIdx.x * 256 + threadIdx.x;
  int b = blockIdx.y;
  float s = 0.f;
  for (int l = 0; l < 512; ++l) s += bufF[((size_t)(b * 512 + l)) * 768 + hh];
  out[b * 768 + hh] = s * (1.f / 512.f);
}

// ---------------------------------------------------------------------------
extern "C" void kernel_launch(void* const* d_in, const int* in_sizes, int n_in,
                              void* d_out, int out_size, void* d_ws, size_t ws_size,
                              hipStream_t stream)
{
  const float* text      = (const float*)d_in[0];
  const float* audio     = (const float*)d_in[1];
  const float* video     = (const float*)d_in[2];
  const float* proj_w    = (const float*)d_in[3];
  const float* proj_b    = (const float*)d_in[4];
  const float* proj_ln_g = (const float*)d_in[5];
  const float* proj_ln_b = (const float*)d_in[6];
  const float* blk_ln_g  = (const float*)d_in[7];
  const float* blk_ln_b  = (const float*)d_in[8];
  const float* in_proj_w = (const float*)d_in[9];
  const float* conv_w    = (const float*)d_in[10];
  const float* conv_b    = (const float*)d_in[11];
  const float* x_proj_w  = (const float*)d_in[12];
  const float* dt_proj_w = (const float*)d_in[13];
  const float* dt_proj_b = (const float*)d_in[14];
  const float* A_log     = (const float*)d_in[15];
  const float* Dv        = (const float*)d_in[16];
  const float* out_projw = (const float*)d_in[17];
  float* out = (float*)d_out;

  // ---- workspace arena (151 MB, lifetimes disjoint within each slab) ----
  char* base = (char*)d_ws;
  const size_t B768 = (size_t)4096 * 768 * 4;       // 12.58 MB fp32
  const size_t BD   = (size_t)4096 * 1536 * 4;      // 25.17 MB fp32
  const size_t P768 = (size_t)4096 * 768 * 2;       // one bf16 [4096][768]
  char* S1 = base;                  // 37.75 MB: modalities -> hA -> xcA -> dtA -> yst
  char* S2 = S1 + 37748736;         // 9.44 MB: JIT-transposed weights
  char* S3 = S2 + 9437184;          // pre -> bufF
  char* S4 = S3 + B768;             // fused
  char* S6 = S4 + B768;             // xbuf -> delta_t
  char* S7 = S6 + BD;               // zt
  char* S8 = S7 + BD;               // xct -> ysA
  char* S9 = S8 + BD;               // dbl [4096][192]

  bf16 *tAh = (bf16*)S1,                *tAl = (bf16*)(S1 + P768);
  bf16 *aAh = (bf16*)(S1 + 2 * P768),   *aAl = (bf16*)(S1 + 3 * P768);
  bf16 *vAh = (bf16*)(S1 + 4 * P768),   *vAl = (bf16*)(S1 + 5 * P768);
  bf16 *hAh = (bf16*)S1,                *hAl = (bf16*)(S1 + P768);
  bf16 *xcAh = (bf16*)S1,               *xcAl = (bf16*)(S1 + (size_t)4096 * 1536 * 2);
  bf16 *dtAh = (bf16*)S1,               *dtAl = (bf16*)(S1 + (size_t)4096 * 64 * 2);
  float* yst = (float*)S1;
  bf16 *pwTh = (bf16*)S2, *pwTl = (bf16*)(S2 + (size_t)768 * 2304 * 2);
  bf16 *ipTh = (bf16*)S2, *ipTl = (bf16*)(S2 + (size_t)3072 * 768 * 2);
  bf16 *xpTh = (bf16*)S2, *xpTl = (bf16*)(S2 + (size_t)192 * 1536 * 2);
  bf16 *dtTh = (bf16*)S2, *dtTl = (bf16*)(S2 + (size_t)1536 * 64 * 2);
  bf16 *opTh = (bf16*)S2, *opTl = (bf16*)(S2 + (size_t)768 * 1536 * 2);
  float* pre   = (float*)S3;  float* bufF = (float*)S3;
  float* fused = (float*)S4;
  float* xbuf  = (float*)S6;  float* delta_t = (float*)S6;
  float* zt    = (float*)S7;
  float* xct   = (float*)S8;
  bf16 *ysAh = (bf16*)S8, *ysAl = (bf16*)(S8 + (size_t)4096 * 1536 * 2);
  float* dbl   = (float*)S9;

  // 1) split modalities to bf16 hi/lo
  split_k<<<12288, 256, 0, stream>>>(text,  tAh, tAl, 768, 768, 768, 4096 * 768);
  split_k<<<12288, 256, 0, stream>>>(audio, aAh, aAl, 768, 768, 768, 4096 * 768);
  split_k<<<12288, 256, 0, stream>>>(video, vAh, vAl, 768, 768, 768, 4096 * 768);
  // 2) proj_w^T
  tsplit_k<<<dim3(36, 12, 1), 256, 0, stream>>>(proj_w, pwTh, pwTl, 2304, 768, 768, 2304, 0, 0);
  // 3) pre = concat @ proj_w + proj_b
  mgemm<128, 64, 2, 2, 1, 1><<<dim3(32, 12), 256, 0, stream>>>(
      tAh, tAl, aAh, aAl, vAh, vAl, pwTh, pwTl, proj_b, nullptr, pre, nullptr, 2304, 768, 768);
  // 4) in_proj_w^T (reuses S2 after gemm1 consumed pwT)
  tsplit_k<<<dim3(12, 48, 1), 256, 0, stream>>>(in_proj_w, ipTh, ipTl, 768, 3072, 3072, 768, 0, 0);
  // 5) fused = LN1(pre); hA = split(LN2(fused))
  ln2_k<<<4096, 256, 0, stream>>>(pre, proj_ln_g, proj_ln_b, blk_ln_g, blk_ln_b, fused, hAh, hAl);
  // 6) [x|z] = h @ in_proj_w: x -> xbuf [4096][1536], z -> zt [B][DIN][L]
  mgemm<128, 128, 2, 2, 0, 5><<<dim3(32, 24), 256, 0, stream>>>(
      hAh, hAl, nullptr, nullptr, nullptr, nullptr, ipTh, ipTl, nullptr, nullptr,
      xbuf, zt, 768, 768, 1536);
  // 7) xct = silu(dwconv(x)+cb) transposed
  conv2_k<<<dim3(8, 24, 8), 256, 0, stream>>>(xbuf, conv_w, conv_b, xct);
  // 8) xcA = split(xct^T per b)  [4096][1536]
  tsplit_k<<<dim3(24, 8, 8), 256, 0, stream>>>(xct, xcAh, xcAl, 1536, 512, 512, 1536,
                                               (size_t)1536 * 512, (size_t)512 * 1536);
  // 9) x_proj_w^T (N padded 176->192)
  tsplit_k<<<dim3(24, 3, 1), 256, 0, stream>>>(x_proj_w, xpTh, xpTl, 1536, 176, 176, 1536, 0, 0);
  // 10) dbl = xconv @ x_proj_w  [4096][192]
  mgemm<64, 64, 4, 1, 0, 0><<<dim3(64, 3), 256, 0, stream>>>(
      xcAh, xcAl, nullptr, nullptr, nullptr, nullptr, xpTh, xpTl, nullptr, nullptr,
      dbl, nullptr, 1536, 1536, 192);
  // 11) dtA = split(dbl[:, :48]) padded K=64
  split_k<<<1024, 256, 0, stream>>>(dbl, dtAh, dtAl, 192, 48, 64, 4096 * 64);
  // 12) dt_proj_w^T (K padded 48->64)
  tsplit_k<<<dim3(1, 24, 1), 256, 0, stream>>>(dt_proj_w, dtTh, dtTl, 48, 1536, 1536, 64, 0, 0);
  // 13) delta_t = softplus(dt @ dt_proj_w + b) transposed [B][DIN][L]
  mgemm<128, 128, 2, 2, 0, 4><<<dim3(32, 12), 256, 0, stream>>>(
      dtAh, dtAl, nullptr, nullptr, nullptr, nullptr, dtTh, dtTl, dt_proj_b, nullptr,
      delta_t, nullptr, 64, 64, 0);
  // 14) selective scan -> yst [B][DIN][L] fp32
  scan2_k<<<3072, 256, 0, stream>>>(delta_t, xct, dbl, zt, A_log, Dv, yst);
  // 15) out_proj_w^T
  tsplit_k<<<dim3(24, 12, 1), 256, 0, stream>>>(out_projw, opTh, opTl, 1536, 768, 768, 1536, 0, 0);
  // 16) ysA = split(yst^T per b)
  tsplit_k<<<dim3(24, 8, 8), 256, 0, stream>>>(yst, ysAh, ysAl, 1536, 512, 512, 1536,
                                               (size_t)1536 * 512, (size_t)512 * 1536);
  // 17) bufF = ys @ out_proj_w + fused
  mgemm<128, 64, 2, 2, 0, 3><<<dim3(32, 12), 256, 0, stream>>>(
      ysAh, ysAl, nullptr, nullptr, nullptr, nullptr, opTh, opTl, nullptr, fused,
      bufF, nullptr, 1536, 1536, 768);
  // 18) mean over L
  mean_k<<<dim3(3, 8), 256, 0, stream>>>(bufF, out);
}

// Round 5
// 756.765 us; speedup vs baseline: 3.1711x; 1.3539x over previous
//
#include <hip/hip_runtime.h>
#include <hip/hip_bf16.h>
#include <cstddef>
#include <cstdint>

// B=8, L=512, H=768, DIN=1536, N=64, R=48, Kc=4. M = B*L = 4096.
#define DIN 1536
#define LSEQ 512

typedef __hip_bfloat16 bf16;
typedef __attribute__((ext_vector_type(8))) short short8x;
typedef __attribute__((ext_vector_type(4))) float f32x4;
typedef const __attribute__((address_space(1))) unsigned int* gp1;
typedef __attribute__((address_space(3))) unsigned int* lp3;

__device__ inline float readlane_f(float v, int l) {
  return __uint_as_float(__builtin_amdgcn_readlane(__float_as_uint(v), l));
}
__device__ inline void gload_lds(const bf16* g, unsigned short* l) {
  __builtin_amdgcn_global_load_lds((gp1)g, (lp3)l, 16, 0, 0);
}
__device__ inline void bsplit(float v, bf16& h, bf16& l) {
  h = __float2bfloat16(v);
  l = __float2bfloat16(v - __bfloat162float(h));
}
__device__ inline float softplusf(float t) {
  return fmaxf(t, 0.f) + log1pf(__expf(-fabsf(t)));
}
// DPP add on the VALU pipe (ctrl must be a compile-time constant).
template<int CTRL>
__device__ inline float dpp_add(float v) {
  int t = __builtin_amdgcn_update_dpp(0, __float_as_int(v), CTRL, 0xf, 0xf, true);
  return v + __int_as_float(t);
}

// ---------------------------------------------------------------------------
// bf16x3 MFMA GEMM. C = A*B fp32-accurate via hi/lo bf16 split (3 MFMA passes).
// A: [M][K] bf16 hi/lo (AMODE 1: concat of 3 segments of 768 along k).
// B: [N][K] bf16 hi/lo (transposed weights).
// LDS layout: [rows][32] bf16, k-chunks (8 bf16) XOR-swizzled by row parity.
// EPI 0: C=acc (ldc)        1: +bias[col]        3: +resid[row*ldc+col]
// EPI 4: softplus(acc+bias[col]) -> transposed [b][col][l]
// EPI 5: col<1536 -> C[row*ldc+col]; else acc -> C2 transposed [b][col-1536][l]
// ---------------------------------------------------------------------------
template<int TBM, int TBN, int WR, int WC, int AMODE, int EPI>
__global__ __launch_bounds__(256) void mgemm(
    const bf16* __restrict__ Ah0, const bf16* __restrict__ Al0,
    const bf16* __restrict__ Ah1, const bf16* __restrict__ Al1,
    const bf16* __restrict__ Ah2, const bf16* __restrict__ Al2,
    const bf16* __restrict__ Bh, const bf16* __restrict__ Bl,
    const float* __restrict__ bias, const float* __restrict__ resid,
    float* __restrict__ C, float* __restrict__ C2,
    int K, int lda, int ldc)
{
  constexpr int SM = TBM / WR, SN = TBN / WC;
  constexpr int T_M = SM / 16, T_N = SN / 16;
  __shared__ unsigned short sAh[TBM * 32], sAl[TBM * 32];
  __shared__ unsigned short sBh[TBN * 32], sBl[TBN * 32];
  const int tid = threadIdx.x;
  const int lane = tid & 63, wid = tid >> 6;
  const int bm = blockIdx.x * TBM, bn = blockIdx.y * TBN;
  const int wr = wid / WC, wc = wid % WC;

  const int stg_m = lane >> 2;
  const int stg_k = ((lane & 3) ^ ((lane >> 3) & 3)) * 8;
  const int fo = (lane & 15) * 64 + ((((lane >> 4) ^ ((lane >> 1) & 3)) & 3) * 16);

  f32x4 acc[T_M][T_N];
  #pragma unroll
  for (int i = 0; i < T_M; ++i)
    #pragma unroll
    for (int j = 0; j < T_N; ++j) acc[i][j] = (f32x4){0.f, 0.f, 0.f, 0.f};

  for (int k0 = 0; k0 < K; k0 += 32) {
    __syncthreads();
    const bf16* pAh; const bf16* pAl; int ka;
    if (AMODE == 1) {
      int seg = k0 / 768;
      pAh = (seg == 0) ? Ah0 : (seg == 1) ? Ah1 : Ah2;
      pAl = (seg == 0) ? Al0 : (seg == 1) ? Al1 : Al2;
      ka = k0 - seg * 768;
    } else { pAh = Ah0; pAl = Al0; ka = k0; }
    #pragma unroll
    for (int it = 0; it < TBM / 64; ++it) {
      int q = it * 4 + wid;
      size_t go = (size_t)(bm + q * 16 + stg_m) * lda + ka + stg_k;
      gload_lds(pAh + go, &sAh[q * 512]);
      gload_lds(pAl + go, &sAl[q * 512]);
    }
    #pragma unroll
    for (int it = 0; it < TBN / 64; ++it) {
      int q = it * 4 + wid;
      size_t go = (size_t)(bn + q * 16 + stg_m) * K + k0 + stg_k;
      gload_lds(Bh + go, &sBh[q * 512]);
      gload_lds(Bl + go, &sBl[q * 512]);
    }
    __syncthreads();

    short8x ah[T_M], al[T_M], bh[T_N], bl[T_N];
    #pragma unroll
    for (int mi = 0; mi < T_M; ++mi) {
      int off = (wr * SM + mi * 16) * 64 + fo;
      ah[mi] = *(const short8x*)((const char*)sAh + off);
      al[mi] = *(const short8x*)((const char*)sAl + off);
    }
    #pragma unroll
    for (int nj = 0; nj < T_N; ++nj) {
      int off = (wc * SN + nj * 16) * 64 + fo;
      bh[nj] = *(const short8x*)((const char*)sBh + off);
      bl[nj] = *(const short8x*)((const char*)sBl + off);
    }
    #pragma unroll
    for (int mi = 0; mi < T_M; ++mi)
      #pragma unroll
      for (int nj = 0; nj < T_N; ++nj) {
        acc[mi][nj] = __builtin_amdgcn_mfma_f32_16x16x32_bf16(ah[mi], bh[nj], acc[mi][nj], 0, 0, 0);
        acc[mi][nj] = __builtin_amdgcn_mfma_f32_16x16x32_bf16(ah[mi], bl[nj], acc[mi][nj], 0, 0, 0);
        acc[mi][nj] = __builtin_amdgcn_mfma_f32_16x16x32_bf16(al[mi], bh[nj], acc[mi][nj], 0, 0, 0);
      }
  }

  const int cl = lane & 15, qd = lane >> 4;
  const int colbase = bn + wc * SN;
  const int rowbase = bm + wr * SM;
  if (EPI == 0 || EPI == 1 || EPI == 3) {
    #pragma unroll
    for (int mi = 0; mi < T_M; ++mi) {
      int r0 = rowbase + mi * 16 + qd * 4;
      #pragma unroll
      for (int nj = 0; nj < T_N; ++nj) {
        int col = colbase + nj * 16 + cl;
        float bv = (EPI == 1) ? bias[col] : 0.f;
        #pragma unroll
        for (int rg = 0; rg < 4; ++rg) {
          float v = acc[mi][nj][rg] + bv;
          if (EPI == 3) v += resid[(size_t)(r0 + rg) * ldc + col];
          C[(size_t)(r0 + rg) * ldc + col] = v;
        }
      }
    }
  } else if (EPI == 4) {
    #pragma unroll
    for (int mi = 0; mi < T_M; ++mi) {
      int m = rowbase + mi * 16 + qd * 4;
      int b = m >> 9, l = m & 511;
      #pragma unroll
      for (int nj = 0; nj < T_N; ++nj) {
        int col = colbase + nj * 16 + cl;
        float bv = bias[col];
        float4 v;
        v.x = softplusf(acc[mi][nj][0] + bv);
        v.y = softplusf(acc[mi][nj][1] + bv);
        v.z = softplusf(acc[mi][nj][2] + bv);
        v.w = softplusf(acc[mi][nj][3] + bv);
        *reinterpret_cast<float4*>(&C[((size_t)b * DIN + col) * LSEQ + l]) = v;
      }
    }
  } else if (EPI == 5) {
    if (bn < 1536) {
      #pragma unroll
      for (int mi = 0; mi < T_M; ++mi) {
        int r0 = rowbase + mi * 16 + qd * 4;
        #pragma unroll
        for (int nj = 0; nj < T_N; ++nj) {
          int col = colbase + nj * 16 + cl;
          #pragma unroll
          for (int rg = 0; rg < 4; ++rg)
            C[(size_t)(r0 + rg) * ldc + col] = acc[mi][nj][rg];
        }
      }
    } else {
      #pragma unroll
      for (int mi = 0; mi < T_M; ++mi) {
        int m = rowbase + mi * 16 + qd * 4;
        int b = m >> 9, l = m & 511;
        #pragma unroll
        for (int nj = 0; nj < T_N; ++nj) {
          int colz = colbase - 1536 + nj * 16 + cl;
          float4 v;
          v.x = acc[mi][nj][0]; v.y = acc[mi][nj][1];
          v.z = acc[mi][nj][2]; v.w = acc[mi][nj][3];
          *reinterpret_cast<float4*>(&C2[((size_t)b * DIN + colz) * LSEQ + l]) = v;
        }
      }
    }
  }
}

// ---------------------------------------------------------------------------
__global__ __launch_bounds__(256) void split_k(
    const float* __restrict__ src, bf16* __restrict__ hi, bf16* __restrict__ lo,
    int ldsrc, int Ws, int Wd, int total)
{
  int idx = blockIdx.x * 256 + threadIdx.x;
  if (idx >= total) return;
  int row = idx / Wd, c = idx - row * Wd;
  float v = (c < Ws) ? src[(size_t)row * ldsrc + c] : 0.f;
  bf16 h, l; bsplit(v, h, l);
  hi[idx] = h; lo[idx] = l;
}

__global__ __launch_bounds__(256) void tsplit_k(
    const float* __restrict__ src, bf16* __restrict__ hi, bf16* __restrict__ lo,
    int P, int Q, int ldsrc, int Ppad, size_t sbs, size_t dbs)
{
  __shared__ float T[64][65];
  src += blockIdx.z * sbs; hi += blockIdx.z * dbs; lo += blockIdx.z * dbs;
  const int p0 = blockIdx.x * 64, q0 = blockIdx.y * 64;
  const int tid = threadIdx.x;
  {
    int j = tid & 63, i0 = tid >> 6;
    for (int i = i0; i < 64; i += 4) {
      int p = p0 + i, q = q0 + j;
      T[i][j] = (p < P && q < Q) ? src[(size_t)p * ldsrc + q] : 0.f;
    }
  }
  __syncthreads();
  {
    int ii = tid & 63, j0 = tid >> 6;
    for (int jj = j0; jj < 64; jj += 4) {
      bf16 h, l; bsplit(T[ii][jj], h, l);
      size_t o = (size_t)(q0 + jj) * Ppad + p0 + ii;
      hi[o] = h; lo[o] = l;
    }
  }
}

// ---------------------------------------------------------------------------
__device__ inline float block_sum256(float s, float* red) {
  #pragma unroll
  for (int o = 32; o > 0; o >>= 1) s += __shfl_xor(s, o, 64);
  int tid = threadIdx.x;
  __syncthreads();
  if ((tid & 63) == 0) red[tid >> 6] = s;
  __syncthreads();
  return red[0] + red[1] + red[2] + red[3];
}

__global__ __launch_bounds__(256) void ln2_k(
    const float* __restrict__ pre,
    const float* __restrict__ g1, const float* __restrict__ b1,
    const float* __restrict__ g2, const float* __restrict__ b2,
    float* __restrict__ fused, bf16* __restrict__ hAh, bf16* __restrict__ hAl)
{
  __shared__ float red[4];
  const int row = blockIdx.x;
  const int tid = threadIdx.x;
  const float* x = pre + (size_t)row * 768;
  float v0 = x[tid], v1 = x[tid + 256], v2 = x[tid + 512];

  float mu = block_sum256(v0 + v1 + v2, red) * (1.f / 768.f);
  float c0 = v0 - mu, c1 = v1 - mu, c2 = v2 - mu;
  float var = block_sum256(c0*c0 + c1*c1 + c2*c2, red) * (1.f / 768.f);
  float r = rsqrtf(var + 1e-5f);
  float f0 = c0 * r * g1[tid] + b1[tid];
  float f1 = c1 * r * g1[tid + 256] + b1[tid + 256];
  float f2 = c2 * r * g1[tid + 512] + b1[tid + 512];
  float* fo = fused + (size_t)row * 768;
  fo[tid] = f0; fo[tid + 256] = f1; fo[tid + 512] = f2;

  float mu2 = block_sum256(f0 + f1 + f2, red) * (1.f / 768.f);
  float d0 = f0 - mu2, d1 = f1 - mu2, d2 = f2 - mu2;
  float var2 = block_sum256(d0*d0 + d1*d1 + d2*d2, red) * (1.f / 768.f);
  float r2 = rsqrtf(var2 + 1e-5f);
  float h0 = d0 * r2 * g2[tid] + b2[tid];
  float h1 = d1 * r2 * g2[tid + 256] + b2[tid + 256];
  float h2 = d2 * r2 * g2[tid + 512] + b2[tid + 512];
  bf16 hh, hl;
  size_t o = (size_t)row * 768;
  bsplit(h0, hh, hl); hAh[o + tid] = hh; hAl[o + tid] = hl;
  bsplit(h1, hh, hl); hAh[o + tid + 256] = hh; hAl[o + tid + 256] = hl;
  bsplit(h2, hh, hl); hAh[o + tid + 512] = hh; hAl[o + tid + 512] = hl;
}

__global__ __launch_bounds__(256) void conv2_k(
    const float* __restrict__ xbuf, const float* __restrict__ w,
    const float* __restrict__ cb, float* __restrict__ xct)
{
  __shared__ float Xs[67][65];
  const int tid = threadIdx.x;
  const int l0 = blockIdx.x * 64;
  const int d0 = blockIdx.y * 64;
  const int b  = blockIdx.z;
  for (int e = tid; e < 67 * 64; e += 256) {
    int r = e >> 6, dd = e & 63;
    int l = l0 - 3 + r;
    Xs[r][dd] = (l >= 0) ? xbuf[((size_t)b * 512 + l) * DIN + d0 + dd] : 0.f;
  }
  __syncthreads();
  const int lane = tid & 63, grp = tid >> 6;
  #pragma unroll
  for (int i = 0; i < 16; ++i) {
    int dd = grp + i * 4;
    int d = d0 + dd;
    float acc = cb[d];
    #pragma unroll
    for (int k = 0; k < 4; ++k)
      acc = fmaf(Xs[lane + k][dd], w[d * 4 + k], acc);
    xct[((size_t)b * DIN + d) * LSEQ + l0 + lane] = acc / (1.f + __expf(-acc));
  }
}

// Selective scan v3: 4 waves/block share b; wave -> d; lane -> state n.
// Per step: 1 ds_read_b64 (B,C interleaved) + DPP-chain reduction on the VALU
// pipe (row_shr 1/2/4/8, row_bcast 15/31 -> total lands in lane 63),
// readlane(63) -> per-lane select. LDS-pipe ops/step: 8 -> 1 vs shfl version.
__global__ __launch_bounds__(256) void scan3_k(
    const float* __restrict__ delta_t, const float* __restrict__ xct,
    const float* __restrict__ dbl, const float* __restrict__ zt,
    const float* __restrict__ A_log, const float* __restrict__ Dv,
    float* __restrict__ ys)
{
  __shared__ float BC[64][128];       // [t][2*lane+{0,1}] = {B, C}  (32 KB)
  const int tid = threadIdx.x;
  const int lane = tid & 63;
  const int wv = tid >> 6;
  const int bid = blockIdx.x;          // 3072 = 8 * 384
  const int b = bid / 384;
  const int d = (bid - b * 384) * 4 + wv;
  const float Ad = -__expf(A_log[d * 64 + lane]);
  const float Dd = Dv[d];
  const size_t strm = ((size_t)b * DIN + d) * LSEQ;
  float h = 0.f;

  for (int l0 = 0; l0 < LSEQ; l0 += 64) {
    __syncthreads();
    #pragma unroll
    for (int i = 0; i < 16; ++i) {
      int t = wv * 16 + i;
      const float* src = dbl + (size_t)(b * LSEQ + l0 + t) * 192;
      float2 v; v.x = src[48 + lane]; v.y = src[112 + lane];
      *reinterpret_cast<float2*>(&BC[t][lane * 2]) = v;
    }
    float dt_v = delta_t[strm + l0 + lane];
    float u_v  = xct[strm + l0 + lane];
    float z_v  = zt[strm + l0 + lane];
    float du_v = dt_v * u_v;
    __syncthreads();

    float ykeep = 0.f;
    #pragma unroll
    for (int t = 0; t < 64; ++t) {
      float dt = readlane_f(dt_v, t);
      float du = readlane_f(du_v, t);
      float2 bc = *reinterpret_cast<const float2*>(&BC[t][lane * 2]);
      float e = __expf(dt * Ad);
      h = fmaf(e, h, du * bc.x);
      float p = h * bc.y;
      p = dpp_add<0x111>(p);   // row_shr:1
      p = dpp_add<0x112>(p);   // row_shr:2
      p = dpp_add<0x114>(p);   // row_shr:4
      p = dpp_add<0x118>(p);   // row_shr:8  -> row sums in lanes 15/31/47/63
      p = dpp_add<0x142>(p);   // row_bcast:15
      p = dpp_add<0x143>(p);   // row_bcast:31 -> full total in lane 63
      float tot = readlane_f(p, 63);
      ykeep = (lane == t) ? tot : ykeep;
    }
    float yv = (ykeep + u_v * Dd) * (z_v / (1.f + __expf(-z_v)));
    ys[strm + l0 + lane] = yv;
  }
}

__global__ __launch_bounds__(256) void mean_k(const float* __restrict__ bufF,
                                              float* __restrict__ out)
{
  int hh = blockIdx.x * 256 + threadIdx.x;
  int b = blockIdx.y;
  float s = 0.f;
  for (int l = 0; l < 512; ++l) s += bufF[((size_t)(b * 512 + l)) * 768 + hh];
  out[b * 768 + hh] = s * (1.f / 512.f);
}

// ---------------------------------------------------------------------------
extern "C" void kernel_launch(void* const* d_in, const int* in_sizes, int n_in,
                              void* d_out, int out_size, void* d_ws, size_t ws_size,
                              hipStream_t stream)
{
  const float* text      = (const float*)d_in[0];
  const float* audio     = (const float*)d_in[1];
  const float* video     = (const float*)d_in[2];
  const float* proj_w    = (const float*)d_in[3];
  const float* proj_b    = (const float*)d_in[4];
  const float* proj_ln_g = (const float*)d_in[5];
  const float* proj_ln_b = (const float*)d_in[6];
  const float* blk_ln_g  = (const float*)d_in[7];
  const float* blk_ln_b  = (const float*)d_in[8];
  const float* in_proj_w = (const float*)d_in[9];
  const float* conv_w    = (const float*)d_in[10];
  const float* conv_b    = (const float*)d_in[11];
  const float* x_proj_w  = (const float*)d_in[12];
  const float* dt_proj_w = (const float*)d_in[13];
  const float* dt_proj_b = (const float*)d_in[14];
  const float* A_log     = (const float*)d_in[15];
  const float* Dv        = (const float*)d_in[16];
  const float* out_projw = (const float*)d_in[17];
  float* out = (float*)d_out;

  // ---- workspace arena (lifetimes disjoint within each slab) ----
  char* base = (char*)d_ws;
  const size_t B768 = (size_t)4096 * 768 * 4;
  const size_t BD   = (size_t)4096 * 1536 * 4;
  const size_t P768 = (size_t)4096 * 768 * 2;
  char* S1 = base;                  // modalities -> hA -> xcA -> dtA -> yst
  char* S2 = S1 + 37748736;         // JIT-transposed weights
  char* S3 = S2 + 9437184;          // pre -> bufF
  char* S4 = S3 + B768;             // fused
  char* S6 = S4 + B768;             // xbuf -> delta_t
  char* S7 = S6 + BD;               // zt
  char* S8 = S7 + BD;               // xct -> ysA
  char* S9 = S8 + BD;               // dbl [4096][192]

  bf16 *tAh = (bf16*)S1,                *tAl = (bf16*)(S1 + P768);
  bf16 *aAh = (bf16*)(S1 + 2 * P768),   *aAl = (bf16*)(S1 + 3 * P768);
  bf16 *vAh = (bf16*)(S1 + 4 * P768),   *vAl = (bf16*)(S1 + 5 * P768);
  bf16 *hAh = (bf16*)S1,                *hAl = (bf16*)(S1 + P768);
  bf16 *xcAh = (bf16*)S1,               *xcAl = (bf16*)(S1 + (size_t)4096 * 1536 * 2);
  bf16 *dtAh = (bf16*)S1,               *dtAl = (bf16*)(S1 + (size_t)4096 * 64 * 2);
  float* yst = (float*)S1;
  bf16 *pwTh = (bf16*)S2, *pwTl = (bf16*)(S2 + (size_t)768 * 2304 * 2);
  bf16 *ipTh = (bf16*)S2, *ipTl = (bf16*)(S2 + (size_t)3072 * 768 * 2);
  bf16 *xpTh = (bf16*)S2, *xpTl = (bf16*)(S2 + (size_t)192 * 1536 * 2);
  bf16 *dtTh = (bf16*)S2, *dtTl = (bf16*)(S2 + (size_t)1536 * 64 * 2);
  bf16 *opTh = (bf16*)S2, *opTl = (bf16*)(S2 + (size_t)768 * 1536 * 2);
  float* pre   = (float*)S3;  float* bufF = (float*)S3;
  float* fused = (float*)S4;
  float* xbuf  = (float*)S6;  float* delta_t = (float*)S6;
  float* zt    = (float*)S7;
  float* xct   = (float*)S8;
  bf16 *ysAh = (bf16*)S8, *ysAl = (bf16*)(S8 + (size_t)4096 * 1536 * 2);
  float* dbl   = (float*)S9;

  // 1) split modalities to bf16 hi/lo
  split_k<<<12288, 256, 0, stream>>>(text,  tAh, tAl, 768, 768, 768, 4096 * 768);
  split_k<<<12288, 256, 0, stream>>>(audio, aAh, aAl, 768, 768, 768, 4096 * 768);
  split_k<<<12288, 256, 0, stream>>>(video, vAh, vAl, 768, 768, 768, 4096 * 768);
  // 2) proj_w^T
  tsplit_k<<<dim3(36, 12, 1), 256, 0, stream>>>(proj_w, pwTh, pwTl, 2304, 768, 768, 2304, 0, 0);
  // 3) pre = concat @ proj_w + proj_b
  mgemm<128, 64, 2, 2, 1, 1><<<dim3(32, 12), 256, 0, stream>>>(
      tAh, tAl, aAh, aAl, vAh, vAl, pwTh, pwTl, proj_b, nullptr, pre, nullptr, 2304, 768, 768);
  // 4) in_proj_w^T
  tsplit_k<<<dim3(12, 48, 1), 256, 0, stream>>>(in_proj_w, ipTh, ipTl, 768, 3072, 3072, 768, 0, 0);
  // 5) fused = LN1(pre); hA = split(LN2(fused))
  ln2_k<<<4096, 256, 0, stream>>>(pre, proj_ln_g, proj_ln_b, blk_ln_g, blk_ln_b, fused, hAh, hAl);
  // 6) [x|z] = h @ in_proj_w: x -> xbuf [4096][1536], z -> zt [B][DIN][L]
  mgemm<128, 128, 2, 2, 0, 5><<<dim3(32, 24), 256, 0, stream>>>(
      hAh, hAl, nullptr, nullptr, nullptr, nullptr, ipTh, ipTl, nullptr, nullptr,
      xbuf, zt, 768, 768, 1536);
  // 7) xct = silu(dwconv(x)+cb) transposed
  conv2_k<<<dim3(8, 24, 8), 256, 0, stream>>>(xbuf, conv_w, conv_b, xct);
  // 8) xcA = split(xct^T per b)
  tsplit_k<<<dim3(24, 8, 8), 256, 0, stream>>>(xct, xcAh, xcAl, 1536, 512, 512, 1536,
                                               (size_t)1536 * 512, (size_t)512 * 1536);
  // 9) x_proj_w^T (N padded 176->192)
  tsplit_k<<<dim3(24, 3, 1), 256, 0, stream>>>(x_proj_w, xpTh, xpTl, 1536, 176, 176, 1536, 0, 0);
  // 10) dbl = xconv @ x_proj_w  [4096][192]
  mgemm<64, 64, 4, 1, 0, 0><<<dim3(64, 3), 256, 0, stream>>>(
      xcAh, xcAl, nullptr, nullptr, nullptr, nullptr, xpTh, xpTl, nullptr, nullptr,
      dbl, nullptr, 1536, 1536, 192);
  // 11) dtA = split(dbl[:, :48]) padded K=64
  split_k<<<1024, 256, 0, stream>>>(dbl, dtAh, dtAl, 192, 48, 64, 4096 * 64);
  // 12) dt_proj_w^T (K padded 48->64)
  tsplit_k<<<dim3(1, 24, 1), 256, 0, stream>>>(dt_proj_w, dtTh, dtTl, 48, 1536, 1536, 64, 0, 0);
  // 13) delta_t = softplus(dt @ dt_proj_w + b) transposed [B][DIN][L]
  mgemm<128, 128, 2, 2, 0, 4><<<dim3(32, 12), 256, 0, stream>>>(
      dtAh, dtAl, nullptr, nullptr, nullptr, nullptr, dtTh, dtTl, dt_proj_b, nullptr,
      delta_t, nullptr, 64, 64, 0);
  // 14) selective scan -> yst [B][DIN][L] fp32
  scan3_k<<<3072, 256, 0, stream>>>(delta_t, xct, dbl, zt, A_log, Dv, yst);
  // 15) out_proj_w^T
  tsplit_k<<<dim3(24, 12, 1), 256, 0, stream>>>(out_projw, opTh, opTl, 1536, 768, 768, 1536, 0, 0);
  // 16) ysA = split(yst^T per b)
  tsplit_k<<<dim3(24, 8, 8), 256, 0, stream>>>(yst, ysAh, ysAl, 1536, 512, 512, 1536,
                                               (size_t)1536 * 512, (size_t)512 * 1536);
  // 17) bufF = ys @ out_proj_w + fused
  mgemm<128, 64, 2, 2, 0, 3><<<dim3(32, 12), 256, 0, stream>>>(
      ysAh, ysAl, nullptr, nullptr, nullptr, nullptr, opTh, opTl, nullptr, fused,
      bufF, nullptr, 1536, 1536, 768);
  // 18) mean over L
  mean_k<<<dim3(3, 8), 256, 0, stream>>>(bufF, out);
}

// Round 6
// 673.717 us; speedup vs baseline: 3.5620x; 1.1233x over previous
//
#include <hip/hip_runtime.h>
#include <hip/hip_bf16.h>
#include <cstddef>
#include <cstdint>

// B=8, L=512, H=768, DIN=1536, N=64, R=48, Kc=4. M = B*L = 4096.
#define DIN 1536
#define LSEQ 512

typedef __hip_bfloat16 bf16;
typedef __attribute__((ext_vector_type(8))) short short8x;
typedef __attribute__((ext_vector_type(4))) float f32x4;
typedef const __attribute__((address_space(1))) unsigned int* gp1;
typedef __attribute__((address_space(3))) unsigned int* lp3;

__device__ inline float readlane_f(float v, int l) {
  return __uint_as_float(__builtin_amdgcn_readlane(__float_as_uint(v), l));
}
__device__ inline void gload_lds(const bf16* g, unsigned short* l) {
  __builtin_amdgcn_global_load_lds((gp1)g, (lp3)l, 16, 0, 0);
}
__device__ inline void bsplit(float v, bf16& h, bf16& l) {
  h = __float2bfloat16(v);
  l = __float2bfloat16(v - __bfloat162float(h));
}
__device__ inline float softplusf(float t) {
  return fmaxf(t, 0.f) + log1pf(__expf(-fabsf(t)));
}
template<int CTRL>
__device__ inline float dpp_add(float v) {
  int t = __builtin_amdgcn_update_dpp(0, __float_as_int(v), CTRL, 0xf, 0xf, true);
  return v + __int_as_float(t);
}
// full-wave sum -> result valid in lane 63
__device__ inline float dpp_wave_sum(float p) {
  p = dpp_add<0x111>(p);  // row_shr:1
  p = dpp_add<0x112>(p);  // row_shr:2
  p = dpp_add<0x114>(p);  // row_shr:4
  p = dpp_add<0x118>(p);  // row_shr:8
  p = dpp_add<0x142>(p);  // row_bcast:15
  p = dpp_add<0x143>(p);  // row_bcast:31
  return p;
}

// ---------------------------------------------------------------------------
// bf16x3 MFMA GEMM. C = A*B fp32-accurate via hi/lo bf16 split (3 MFMA passes).
// A: [M][K] bf16 hi/lo (AMODE 1: concat of 3 segments of 768 along k).
// B: [N][K] bf16 hi/lo (transposed weights).
// EPI 1: C = acc + bias[col]
// EPI 4: softplus(acc+bias[col]) -> transposed [b][col][l]
// EPI 5: col<1536 -> C[row*ldc+col]; else acc -> C2 transposed [b][col-1536][l]
// EPI 6: C[row*192+col] = acc (fp32); col<64 -> Oh/Ol[row*64+col] = split(acc)
//        (cols 48..63 zero-filled)  [x_proj + dtA fusion]
// ---------------------------------------------------------------------------
template<int TBM, int TBN, int WR, int WC, int AMODE, int EPI>
__global__ __launch_bounds__(WR*WC*64) void mgemm(
    const bf16* __restrict__ Ah0, const bf16* __restrict__ Al0,
    const bf16* __restrict__ Ah1, const bf16* __restrict__ Al1,
    const bf16* __restrict__ Ah2, const bf16* __restrict__ Al2,
    const bf16* __restrict__ Bh, const bf16* __restrict__ Bl,
    const float* __restrict__ bias,
    float* __restrict__ C, float* __restrict__ C2,
    bf16* __restrict__ Oh, bf16* __restrict__ Ol,
    int K, int lda, int ldc)
{
  constexpr int NW = WR * WC;
  constexpr int SM = TBM / WR, SN = TBN / WC;
  constexpr int T_M = SM / 16, T_N = SN / 16;
  __shared__ unsigned short sAh[TBM * 32], sAl[TBM * 32];
  __shared__ unsigned short sBh[TBN * 32], sBl[TBN * 32];
  const int tid = threadIdx.x;
  const int lane = tid & 63, wid = tid >> 6;
  const int bm = blockIdx.x * TBM, bn = blockIdx.y * TBN;
  const int wr = wid / WC, wc = wid % WC;

  const int stg_m = lane >> 2;
  const int stg_k = ((lane & 3) ^ ((lane >> 3) & 3)) * 8;
  const int fo = (lane & 15) * 64 + ((((lane >> 4) ^ ((lane >> 1) & 3)) & 3) * 16);

  f32x4 acc[T_M][T_N];
  #pragma unroll
  for (int i = 0; i < T_M; ++i)
    #pragma unroll
    for (int j = 0; j < T_N; ++j) acc[i][j] = (f32x4){0.f, 0.f, 0.f, 0.f};

  for (int k0 = 0; k0 < K; k0 += 32) {
    __syncthreads();
    const bf16* pAh; const bf16* pAl; int ka;
    if (AMODE == 1) {
      int seg = k0 / 768;
      pAh = (seg == 0) ? Ah0 : (seg == 1) ? Ah1 : Ah2;
      pAl = (seg == 0) ? Al0 : (seg == 1) ? Al1 : Al2;
      ka = k0 - seg * 768;
    } else { pAh = Ah0; pAl = Al0; ka = k0; }
    #pragma unroll
    for (int q = wid; q < TBM / 16; q += NW) {
      size_t go = (size_t)(bm + q * 16 + stg_m) * lda + ka + stg_k;
      gload_lds(pAh + go, &sAh[q * 512]);
      gload_lds(pAl + go, &sAl[q * 512]);
    }
    #pragma unroll
    for (int q = wid; q < TBN / 16; q += NW) {
      size_t go = (size_t)(bn + q * 16 + stg_m) * K + k0 + stg_k;
      gload_lds(Bh + go, &sBh[q * 512]);
      gload_lds(Bl + go, &sBl[q * 512]);
    }
    __syncthreads();

    short8x ah[T_M], al[T_M], bh[T_N], bl[T_N];
    #pragma unroll
    for (int mi = 0; mi < T_M; ++mi) {
      int off = (wr * SM + mi * 16) * 64 + fo;
      ah[mi] = *(const short8x*)((const char*)sAh + off);
      al[mi] = *(const short8x*)((const char*)sAl + off);
    }
    #pragma unroll
    for (int nj = 0; nj < T_N; ++nj) {
      int off = (wc * SN + nj * 16) * 64 + fo;
      bh[nj] = *(const short8x*)((const char*)sBh + off);
      bl[nj] = *(const short8x*)((const char*)sBl + off);
    }
    #pragma unroll
    for (int mi = 0; mi < T_M; ++mi)
      #pragma unroll
      for (int nj = 0; nj < T_N; ++nj) {
        acc[mi][nj] = __builtin_amdgcn_mfma_f32_16x16x32_bf16(ah[mi], bh[nj], acc[mi][nj], 0, 0, 0);
        acc[mi][nj] = __builtin_amdgcn_mfma_f32_16x16x32_bf16(ah[mi], bl[nj], acc[mi][nj], 0, 0, 0);
        acc[mi][nj] = __builtin_amdgcn_mfma_f32_16x16x32_bf16(al[mi], bh[nj], acc[mi][nj], 0, 0, 0);
      }
  }

  // epilogue — C/D layout: col = lane&15, row = (lane>>4)*4 + reg
  const int cl = lane & 15, qd = lane >> 4;
  const int colbase = bn + wc * SN;
  const int rowbase = bm + wr * SM;
  if (EPI == 1) {
    #pragma unroll
    for (int mi = 0; mi < T_M; ++mi) {
      int r0 = rowbase + mi * 16 + qd * 4;
      #pragma unroll
      for (int nj = 0; nj < T_N; ++nj) {
        int col = colbase + nj * 16 + cl;
        float bv = bias[col];
        #pragma unroll
        for (int rg = 0; rg < 4; ++rg)
          C[(size_t)(r0 + rg) * ldc + col] = acc[mi][nj][rg] + bv;
      }
    }
  } else if (EPI == 4) {
    #pragma unroll
    for (int mi = 0; mi < T_M; ++mi) {
      int m = rowbase + mi * 16 + qd * 4;
      int b = m >> 9, l = m & 511;
      #pragma unroll
      for (int nj = 0; nj < T_N; ++nj) {
        int col = colbase + nj * 16 + cl;
        float bv = bias[col];
        float4 v;
        v.x = softplusf(acc[mi][nj][0] + bv);
        v.y = softplusf(acc[mi][nj][1] + bv);
        v.z = softplusf(acc[mi][nj][2] + bv);
        v.w = softplusf(acc[mi][nj][3] + bv);
        *reinterpret_cast<float4*>(&C[((size_t)b * DIN + col) * LSEQ + l]) = v;
      }
    }
  } else if (EPI == 5) {
    if (bn < 1536) {
      #pragma unroll
      for (int mi = 0; mi < T_M; ++mi) {
        int r0 = rowbase + mi * 16 + qd * 4;
        #pragma unroll
        for (int nj = 0; nj < T_N; ++nj) {
          int col = colbase + nj * 16 + cl;
          #pragma unroll
          for (int rg = 0; rg < 4; ++rg)
            C[(size_t)(r0 + rg) * ldc + col] = acc[mi][nj][rg];
        }
      }
    } else {
      #pragma unroll
      for (int mi = 0; mi < T_M; ++mi) {
        int m = rowbase + mi * 16 + qd * 4;
        int b = m >> 9, l = m & 511;
        #pragma unroll
        for (int nj = 0; nj < T_N; ++nj) {
          int colz = colbase - 1536 + nj * 16 + cl;
          float4 v;
          v.x = acc[mi][nj][0]; v.y = acc[mi][nj][1];
          v.z = acc[mi][nj][2]; v.w = acc[mi][nj][3];
          *reinterpret_cast<float4*>(&C2[((size_t)b * DIN + colz) * LSEQ + l]) = v;
        }
      }
    }
  } else if (EPI == 6) {
    #pragma unroll
    for (int mi = 0; mi < T_M; ++mi) {
      int r0 = rowbase + mi * 16 + qd * 4;
      #pragma unroll
      for (int nj = 0; nj < T_N; ++nj) {
        int col = colbase + nj * 16 + cl;
        #pragma unroll
        for (int rg = 0; rg < 4; ++rg) {
          float v = acc[mi][nj][rg];
          C[(size_t)(r0 + rg) * 192 + col] = v;
          if (col < 64) {
            bf16 h, l;
            if (col < 48) bsplit(v, h, l);
            else { h = __float2bfloat16(0.f); l = h; }
            Oh[(size_t)(r0 + rg) * 64 + col] = h;
            Ol[(size_t)(r0 + rg) * 64 + col] = l;
          }
        }
      }
    }
  }
}

// ---------------------------------------------------------------------------
// All three modality tensors -> bf16 hi/lo in one launch.
__global__ __launch_bounds__(256) void split3_k(
    const float* __restrict__ s0, const float* __restrict__ s1,
    const float* __restrict__ s2, bf16* __restrict__ dst)  // dst: 3 x [hi|lo] blocks
{
  const int per = 4096 * 768 / 256;       // 12288 blocks per modality
  int seg = blockIdx.x / per;
  int idx = (blockIdx.x - seg * per) * 256 + threadIdx.x;
  const float* src = (seg == 0) ? s0 : (seg == 1) ? s1 : s2;
  bf16* hi = dst + (size_t)seg * 2 * 4096 * 768;
  bf16* lo = hi + (size_t)4096 * 768;
  bf16 h, l; bsplit(src[idx], h, l);
  hi[idx] = h; lo[idx] = l;
}

// All four weight transposes+splits in one launch (block-range dispatch).
__global__ __launch_bounds__(256) void wprep_k(
    const float* __restrict__ pw, const float* __restrict__ ipw,
    const float* __restrict__ xpw, const float* __restrict__ dtw,
    bf16* pwTh, bf16* pwTl, bf16* ipTh, bf16* ipTl,
    bf16* xpTh, bf16* xpTl, bf16* dtTh, bf16* dtTl)
{
  __shared__ float T[64][65];
  const int id = blockIdx.x, tid = threadIdx.x;
  const float* src; bf16 *hi, *lo; int P, Q, ld, Ppad, px, qx;
  if (id < 432)       { src = pw;  hi = pwTh; lo = pwTl; P = 2304; Q = 768;  ld = 768;  Ppad = 2304; px = id % 36;          qx = id / 36; }
  else if (id < 1008) { int i = id - 432;  src = ipw; hi = ipTh; lo = ipTl; P = 768;  Q = 3072; ld = 3072; Ppad = 768;  px = i % 12; qx = i / 12; }
  else if (id < 1080) { int i = id - 1008; src = xpw; hi = xpTh; lo = xpTl; P = 1536; Q = 176;  ld = 176;  Ppad = 1536; px = i % 24; qx = i / 24; }
  else                { int i = id - 1080; src = dtw; hi = dtTh; lo = dtTl; P = 48;   Q = 1536; ld = 1536; Ppad = 64;   px = 0;      qx = i; }
  const int p0 = px * 64, q0 = qx * 64;
  {
    int j = tid & 63, i0 = tid >> 6;
    for (int i = i0; i < 64; i += 4) {
      int p = p0 + i, q = q0 + j;
      T[i][j] = (p < P && q < Q) ? src[(size_t)p * ld + q] : 0.f;
    }
  }
  __syncthreads();
  {
    int ii = tid & 63, j0 = tid >> 6;
    for (int jj = j0; jj < 64; jj += 4) {
      bf16 h, l; bsplit(T[ii][jj], h, l);
      size_t o = (size_t)(q0 + jj) * Ppad + p0 + ii;
      hi[o] = h; lo[o] = l;
    }
  }
}

// ---------------------------------------------------------------------------
__device__ inline float block_sum256(float s, float* red) {
  #pragma unroll
  for (int o = 32; o > 0; o >>= 1) s += __shfl_xor(s, o, 64);
  int tid = threadIdx.x;
  __syncthreads();
  if ((tid & 63) == 0) red[tid >> 6] = s;
  __syncthreads();
  return red[0] + red[1] + red[2] + red[3];
}

__global__ __launch_bounds__(256) void ln2_k(
    const float* __restrict__ pre,
    const float* __restrict__ g1, const float* __restrict__ b1,
    const float* __restrict__ g2, const float* __restrict__ b2,
    float* __restrict__ fused, bf16* __restrict__ hAh, bf16* __restrict__ hAl)
{
  __shared__ float red[4];
  const int row = blockIdx.x;
  const int tid = threadIdx.x;
  const float* x = pre + (size_t)row * 768;
  float v0 = x[tid], v1 = x[tid + 256], v2 = x[tid + 512];

  float mu = block_sum256(v0 + v1 + v2, red) * (1.f / 768.f);
  float c0 = v0 - mu, c1 = v1 - mu, c2 = v2 - mu;
  float var = block_sum256(c0*c0 + c1*c1 + c2*c2, red) * (1.f / 768.f);
  float r = rsqrtf(var + 1e-5f);
  float f0 = c0 * r * g1[tid] + b1[tid];
  float f1 = c1 * r * g1[tid + 256] + b1[tid + 256];
  float f2 = c2 * r * g1[tid + 512] + b1[tid + 512];
  float* fo = fused + (size_t)row * 768;
  fo[tid] = f0; fo[tid + 256] = f1; fo[tid + 512] = f2;

  float mu2 = block_sum256(f0 + f1 + f2, red) * (1.f / 768.f);
  float d0 = f0 - mu2, d1 = f1 - mu2, d2 = f2 - mu2;
  float var2 = block_sum256(d0*d0 + d1*d1 + d2*d2, red) * (1.f / 768.f);
  float r2 = rsqrtf(var2 + 1e-5f);
  float h0 = d0 * r2 * g2[tid] + b2[tid];
  float h1 = d1 * r2 * g2[tid + 256] + b2[tid + 256];
  float h2 = d2 * r2 * g2[tid + 512] + b2[tid + 512];
  bf16 hh, hl;
  size_t o = (size_t)row * 768;
  bsplit(h0, hh, hl); hAh[o + tid] = hh; hAl[o + tid] = hl;
  bsplit(h1, hh, hl); hAh[o + tid + 256] = hh; hAl[o + tid + 256] = hl;
  bsplit(h2, hh, hl); hAh[o + tid + 512] = hh; hAl[o + tid + 512] = hl;
}

// Causal depthwise conv (K=4) + bias + silu.
// Outputs xct [B][DIN][L] fp32 (scan) AND xcA [row][DIN] bf16 hi/lo (x_proj A).
__global__ __launch_bounds__(256) void conv2x_k(
    const float* __restrict__ xbuf, const float* __restrict__ w,
    const float* __restrict__ cb, float* __restrict__ xct,
    bf16* __restrict__ xcAh, bf16* __restrict__ xcAl)
{
  __shared__ float Xs[67][65];
  __shared__ float Ys[64][65];
  const int tid = threadIdx.x;
  const int l0 = blockIdx.x * 64;
  const int d0 = blockIdx.y * 64;
  const int b  = blockIdx.z;
  for (int e = tid; e < 67 * 64; e += 256) {
    int r = e >> 6, dd = e & 63;
    int l = l0 - 3 + r;
    Xs[r][dd] = (l >= 0) ? xbuf[((size_t)b * 512 + l) * DIN + d0 + dd] : 0.f;
  }
  __syncthreads();
  {
    const int lane = tid & 63, grp = tid >> 6;
    #pragma unroll
    for (int i = 0; i < 16; ++i) {
      int dd = grp + i * 4;
      int d = d0 + dd;
      float acc = cb[d];
      #pragma unroll
      for (int k = 0; k < 4; ++k)
        acc = fmaf(Xs[lane + k][dd], w[d * 4 + k], acc);
      float v = acc / (1.f + __expf(-acc));
      xct[((size_t)b * DIN + d) * LSEQ + l0 + lane] = v;
      Ys[lane][dd] = v;
    }
  }
  __syncthreads();
  {
    const int dd = tid & 63, lg = tid >> 6;
    #pragma unroll
    for (int j = 0; j < 16; ++j) {
      int l = lg * 16 + j;
      bf16 h, lo; bsplit(Ys[l][dd], h, lo);
      size_t o = (size_t)(b * 512 + l0 + l) * DIN + d0 + dd;
      xcAh[o] = h; xcAl[o] = lo;
    }
  }
}

// Selective scan v4: 4 waves/block share b; wave -> d; lane -> state n.
// 2 timesteps per iteration with interleaved DPP trees (fills DPP hazard
// slots). Only the L-sum of y per (b,d) is emitted (mean commutes with
// out_proj), so no per-step global store at all.
__global__ __launch_bounds__(256) void scan4_k(
    const float* __restrict__ delta_t, const float* __restrict__ xct,
    const float* __restrict__ dbl, const float* __restrict__ zt,
    const float* __restrict__ A_log, const float* __restrict__ Dv,
    float* __restrict__ ysbar)
{
  __shared__ float BC[64][128];       // [t][2*lane+{0,1}] = {B, C}  (32 KB)
  const int tid = threadIdx.x;
  const int lane = tid & 63;
  const int wv = tid >> 6;
  const int bid = blockIdx.x;          // 3072 = 8 * 384
  const int b = bid / 384;
  const int d = (bid - b * 384) * 4 + wv;
  const float Ad = -__expf(A_log[d * 64 + lane]);
  const float Dd = Dv[d];
  const size_t strm = ((size_t)b * DIN + d) * LSEQ;
  float h = 0.f;
  float ysum = 0.f;

  for (int l0 = 0; l0 < LSEQ; l0 += 64) {
    __syncthreads();
    #pragma unroll
    for (int i = 0; i < 16; ++i) {
      int t = wv * 16 + i;
      const float* src = dbl + (size_t)(b * LSEQ + l0 + t) * 192;
      float2 v; v.x = src[48 + lane]; v.y = src[112 + lane];
      *reinterpret_cast<float2*>(&BC[t][lane * 2]) = v;
    }
    float dt_v = delta_t[strm + l0 + lane];
    float u_v  = xct[strm + l0 + lane];
    float z_v  = zt[strm + l0 + lane];
    float du_v = dt_v * u_v;
    __syncthreads();

    float yk = 0.f;
    #pragma unroll
    for (int t2 = 0; t2 < 32; ++t2) {
      const int t0 = 2 * t2, t1 = t0 + 1;
      float dta = readlane_f(dt_v, t0), dua = readlane_f(du_v, t0);
      float dtb = readlane_f(dt_v, t1), dub = readlane_f(du_v, t1);
      float2 bca = *reinterpret_cast<const float2*>(&BC[t0][lane * 2]);
      float2 bcb = *reinterpret_cast<const float2*>(&BC[t1][lane * 2]);
      float ea = __expf(dta * Ad);
      float eb = __expf(dtb * Ad);
      h = fmaf(ea, h, dua * bca.x);
      float pa = h * bca.y;
      h = fmaf(eb, h, dub * bcb.x);
      float pb = h * bcb.y;
      // interleaved DPP trees
      pa = dpp_add<0x111>(pa); pb = dpp_add<0x111>(pb);
      pa = dpp_add<0x112>(pa); pb = dpp_add<0x112>(pb);
      pa = dpp_add<0x114>(pa); pb = dpp_add<0x114>(pb);
      pa = dpp_add<0x118>(pa); pb = dpp_add<0x118>(pb);
      pa = dpp_add<0x142>(pa); pb = dpp_add<0x142>(pb);
      pa = dpp_add<0x143>(pa); pb = dpp_add<0x143>(pb);
      float ta_ = readlane_f(pa, 63);
      float tb_ = readlane_f(pb, 63);
      yk = (lane == t0) ? ta_ : yk;
      yk = (lane == t1) ? tb_ : yk;
    }
    float yv = (yk + u_v * Dd) * (z_v / (1.f + __expf(-z_v)));
    ysum += yv;
  }
  // wave-reduce ysum over lanes (l positions) -> one value per (b,d)
  float tot = readlane_f(dpp_wave_sum(ysum), 63);
  if (lane == 0) ysbar[b * 1536 + d] = tot;
}

// out[b][c] = (sum_l fused[b,l,c] + sum_d ysbar[b,d]*W[d,c]) / 512
__global__ __launch_bounds__(256) void final_k(
    const float* __restrict__ fused, const float* __restrict__ ysbar,
    const float* __restrict__ W, float* __restrict__ out)
{
  __shared__ float ys[1536];
  const int b = blockIdx.y;
  const int c = blockIdx.x * 256 + threadIdx.x;
  for (int i = threadIdx.x; i < 1536; i += 256) ys[i] = ysbar[b * 1536 + i];
  __syncthreads();
  float sf = 0.f;
  for (int l = 0; l < 512; ++l) sf += fused[(size_t)((b << 9) + l) * 768 + c];
  float dot = 0.f;
  for (int d = 0; d < 1536; ++d) dot = fmaf(ys[d], W[(size_t)d * 768 + c], dot);
  out[b * 768 + c] = (sf + dot) * (1.f / 512.f);
}

// ---------------------------------------------------------------------------
extern "C" void kernel_launch(void* const* d_in, const int* in_sizes, int n_in,
                              void* d_out, int out_size, void* d_ws, size_t ws_size,
                              hipStream_t stream)
{
  const float* text      = (const float*)d_in[0];
  const float* audio     = (const float*)d_in[1];
  const float* video     = (const float*)d_in[2];
  const float* proj_w    = (const float*)d_in[3];
  const float* proj_b    = (const float*)d_in[4];
  const float* proj_ln_g = (const float*)d_in[5];
  const float* proj_ln_b = (const float*)d_in[6];
  const float* blk_ln_g  = (const float*)d_in[7];
  const float* blk_ln_b  = (const float*)d_in[8];
  const float* in_proj_w = (const float*)d_in[9];
  const float* conv_w    = (const float*)d_in[10];
  const float* conv_b    = (const float*)d_in[11];
  const float* x_proj_w  = (const float*)d_in[12];
  const float* dt_proj_w = (const float*)d_in[13];
  const float* dt_proj_b = (const float*)d_in[14];
  const float* A_log     = (const float*)d_in[15];
  const float* Dv        = (const float*)d_in[16];
  const float* out_projw = (const float*)d_in[17];
  float* out = (float*)d_out;

  // ---- workspace arena ----
  char* p = (char*)d_ws;
  const size_t P768 = (size_t)4096 * 768 * 2;     // one bf16 [4096][768]
  char* S1 = p; p += 6 * P768;                    // modality splits -> hA -> xcA (37.75 MB)
  char* SW = p; p += 18087936;                    // weights (all live together)
  char* S3 = p; p += (size_t)4096 * 768 * 4;      // pre
  char* S4 = p; p += (size_t)4096 * 768 * 4;      // fused
  char* S6 = p; p += (size_t)4096 * 1536 * 4;     // xbuf -> delta_t
  char* S7 = p; p += (size_t)4096 * 1536 * 4;     // zt
  char* S8 = p; p += (size_t)4096 * 1536 * 4;     // xct
  char* SD = p; p += (size_t)4096 * 64 * 4;       // dtA hi/lo
  char* S9 = p; p += (size_t)4096 * 192 * 4;      // dbl
  char* SY = p; p += 12288 * 4;                   // ysbar

  bf16* modspl = (bf16*)S1;  // 3 x [hi|lo]
  bf16 *tAh = (bf16*)S1,              *tAl = (bf16*)(S1 + P768);
  bf16 *aAh = (bf16*)(S1 + 2 * P768), *aAl = (bf16*)(S1 + 3 * P768);
  bf16 *vAh = (bf16*)(S1 + 4 * P768), *vAl = (bf16*)(S1 + 5 * P768);
  bf16 *hAh = (bf16*)S1,              *hAl = (bf16*)(S1 + P768);
  bf16 *xcAh = (bf16*)S1,             *xcAl = (bf16*)(S1 + (size_t)4096 * 1536 * 2);
  bf16 *pwTh = (bf16*)SW,                    *pwTl = pwTh + (size_t)768 * 2304;
  bf16 *ipTh = pwTl + (size_t)768 * 2304,    *ipTl = ipTh + (size_t)3072 * 768;
  bf16 *xpTh = ipTl + (size_t)3072 * 768,    *xpTl = xpTh + (size_t)192 * 1536;
  bf16 *dtTh = xpTl + (size_t)192 * 1536,    *dtTl = dtTh + (size_t)1536 * 64;
  float* pre     = (float*)S3;
  float* fused   = (float*)S4;
  float* xbuf    = (float*)S6;  float* delta_t = (float*)S6;
  float* zt      = (float*)S7;
  float* xct     = (float*)S8;
  bf16 *dtAh = (bf16*)SD, *dtAl = (bf16*)(SD + (size_t)4096 * 64 * 2);
  float* dbl     = (float*)S9;
  float* ysbar   = (float*)SY;

  // 1) all three modality splits
  split3_k<<<36864, 256, 0, stream>>>(text, audio, video, modspl);
  // 2) all four weight transposes+splits
  wprep_k<<<1104, 256, 0, stream>>>(proj_w, in_proj_w, x_proj_w, dt_proj_w,
                                    pwTh, pwTl, ipTh, ipTl, xpTh, xpTl, dtTh, dtTl);
  // 3) pre = concat @ proj_w + proj_b   (8-wave blocks for occupancy)
  mgemm<128, 64, 4, 2, 1, 1><<<dim3(32, 12), 512, 0, stream>>>(
      tAh, tAl, aAh, aAl, vAh, vAl, pwTh, pwTl, proj_b,
      pre, nullptr, nullptr, nullptr, 2304, 768, 768);
  // 4) fused = LN1(pre); hA = split(LN2(fused))
  ln2_k<<<4096, 256, 0, stream>>>(pre, proj_ln_g, proj_ln_b, blk_ln_g, blk_ln_b, fused, hAh, hAl);
  // 5) [x|z] = h @ in_proj_w: x -> xbuf [4096][1536], z -> zt [B][DIN][L]
  mgemm<128, 128, 2, 2, 0, 5><<<dim3(32, 24), 256, 0, stream>>>(
      hAh, hAl, nullptr, nullptr, nullptr, nullptr, ipTh, ipTl, nullptr,
      xbuf, zt, nullptr, nullptr, 768, 768, 1536);
  // 6) xct = silu(dwconv(x)+cb) transposed; xcA = split(xct) row-major
  conv2x_k<<<dim3(8, 24, 8), 256, 0, stream>>>(xbuf, conv_w, conv_b, xct, xcAh, xcAl);
  // 7) dbl = xconv @ x_proj_w [4096][192] fp32 + dtA hi/lo (cols<48, pad 64)
  mgemm<64, 64, 4, 2, 0, 6><<<dim3(64, 3), 512, 0, stream>>>(
      xcAh, xcAl, nullptr, nullptr, nullptr, nullptr, xpTh, xpTl, nullptr,
      dbl, nullptr, dtAh, dtAl, 1536, 1536, 192);
  // 8) delta_t = softplus(dt @ dt_proj_w + b) transposed [B][DIN][L]
  mgemm<128, 64, 4, 2, 0, 4><<<dim3(32, 24), 512, 0, stream>>>(
      dtAh, dtAl, nullptr, nullptr, nullptr, nullptr, dtTh, dtTl, dt_proj_b,
      delta_t, nullptr, nullptr, nullptr, 64, 64, 0);
  // 9) selective scan -> ysbar[b][d] = sum_l y
  scan4_k<<<3072, 256, 0, stream>>>(delta_t, xct, dbl, zt, A_log, Dv, ysbar);
  // 10) out = (sum_l fused + ysbar @ out_proj_w) / 512
  final_k<<<dim3(3, 8), 256, 0, stream>>>(fused, ysbar, out_projw, out);
}

// Round 7
// 663.726 us; speedup vs baseline: 3.6156x; 1.0151x over previous
//
#include <hip/hip_runtime.h>
#include <hip/hip_bf16.h>
#include <cstddef>
#include <cstdint>

// B=8, L=512, H=768, DIN=1536, N=64, R=48, Kc=4. M = B*L = 4096.
#define DIN 1536
#define LSEQ 512

typedef __hip_bfloat16 bf16;
typedef __attribute__((ext_vector_type(8))) short short8x;
typedef __attribute__((ext_vector_type(4))) float f32x4;
typedef const __attribute__((address_space(1))) unsigned int* gp1;
typedef __attribute__((address_space(3))) unsigned int* lp3;

__device__ inline float readlane_f(float v, int l) {
  return __uint_as_float(__builtin_amdgcn_readlane(__float_as_uint(v), l));
}
__device__ inline void gload_lds(const bf16* g, unsigned short* l) {
  __builtin_amdgcn_global_load_lds((gp1)g, (lp3)l, 16, 0, 0);
}
__device__ inline void bsplit(float v, bf16& h, bf16& l) {
  h = __float2bfloat16(v);
  l = __float2bfloat16(v - __bfloat162float(h));
}
__device__ inline float softplusf(float t) {
  return fmaxf(t, 0.f) + log1pf(__expf(-fabsf(t)));
}
template<int CTRL>
__device__ inline float dpp_add(float v) {
  int t = __builtin_amdgcn_update_dpp(0, __float_as_int(v), CTRL, 0xf, 0xf, true);
  return v + __int_as_float(t);
}
// full-wave sum -> result valid in lane 63
__device__ inline float dpp_wave_sum(float p) {
  p = dpp_add<0x111>(p);  // row_shr:1
  p = dpp_add<0x112>(p);  // row_shr:2
  p = dpp_add<0x114>(p);  // row_shr:4
  p = dpp_add<0x118>(p);  // row_shr:8
  p = dpp_add<0x142>(p);  // row_bcast:15
  p = dpp_add<0x143>(p);  // row_bcast:31
  return p;
}

// ---------------------------------------------------------------------------
// bf16x3 MFMA GEMM. C = A*B fp32-accurate via hi/lo bf16 split (3 MFMA passes).
// A: [M][K] bf16 hi/lo (AMODE 1: concat of 3 segments of 768 along k).
// B: [N][K] bf16 hi/lo (transposed weights).
// EPI 1: C = acc + bias[col]
// EPI 4: softplus(acc+bias[col]) -> transposed [b][col][l]
// EPI 5: col<1536 -> C[row*ldc+col]; else acc -> C2 transposed [b][col-1536][l]
// EPI 6: C[row*192+col] = acc (fp32); col<64 -> Oh/Ol[row*64+col] = split(acc)
// ---------------------------------------------------------------------------
template<int TBM, int TBN, int WR, int WC, int AMODE, int EPI>
__global__ __launch_bounds__(WR*WC*64) void mgemm(
    const bf16* __restrict__ Ah0, const bf16* __restrict__ Al0,
    const bf16* __restrict__ Ah1, const bf16* __restrict__ Al1,
    const bf16* __restrict__ Ah2, const bf16* __restrict__ Al2,
    const bf16* __restrict__ Bh, const bf16* __restrict__ Bl,
    const float* __restrict__ bias,
    float* __restrict__ C, float* __restrict__ C2,
    bf16* __restrict__ Oh, bf16* __restrict__ Ol,
    int K, int lda, int ldc)
{
  constexpr int NW = WR * WC;
  constexpr int SM = TBM / WR, SN = TBN / WC;
  constexpr int T_M = SM / 16, T_N = SN / 16;
  __shared__ unsigned short sAh[TBM * 32], sAl[TBM * 32];
  __shared__ unsigned short sBh[TBN * 32], sBl[TBN * 32];
  const int tid = threadIdx.x;
  const int lane = tid & 63, wid = tid >> 6;
  const int bm = blockIdx.x * TBM, bn = blockIdx.y * TBN;
  const int wr = wid / WC, wc = wid % WC;

  const int stg_m = lane >> 2;
  const int stg_k = ((lane & 3) ^ ((lane >> 3) & 3)) * 8;
  const int fo = (lane & 15) * 64 + ((((lane >> 4) ^ ((lane >> 1) & 3)) & 3) * 16);

  f32x4 acc[T_M][T_N];
  #pragma unroll
  for (int i = 0; i < T_M; ++i)
    #pragma unroll
    for (int j = 0; j < T_N; ++j) acc[i][j] = (f32x4){0.f, 0.f, 0.f, 0.f};

  for (int k0 = 0; k0 < K; k0 += 32) {
    __syncthreads();
    const bf16* pAh; const bf16* pAl; int ka;
    if (AMODE == 1) {
      int seg = k0 / 768;
      pAh = (seg == 0) ? Ah0 : (seg == 1) ? Ah1 : Ah2;
      pAl = (seg == 0) ? Al0 : (seg == 1) ? Al1 : Al2;
      ka = k0 - seg * 768;
    } else { pAh = Ah0; pAl = Al0; ka = k0; }
    #pragma unroll
    for (int q = wid; q < TBM / 16; q += NW) {
      size_t go = (size_t)(bm + q * 16 + stg_m) * lda + ka + stg_k;
      gload_lds(pAh + go, &sAh[q * 512]);
      gload_lds(pAl + go, &sAl[q * 512]);
    }
    #pragma unroll
    for (int q = wid; q < TBN / 16; q += NW) {
      size_t go = (size_t)(bn + q * 16 + stg_m) * K + k0 + stg_k;
      gload_lds(Bh + go, &sBh[q * 512]);
      gload_lds(Bl + go, &sBl[q * 512]);
    }
    __syncthreads();

    short8x ah[T_M], al[T_M], bh[T_N], bl[T_N];
    #pragma unroll
    for (int mi = 0; mi < T_M; ++mi) {
      int off = (wr * SM + mi * 16) * 64 + fo;
      ah[mi] = *(const short8x*)((const char*)sAh + off);
      al[mi] = *(const short8x*)((const char*)sAl + off);
    }
    #pragma unroll
    for (int nj = 0; nj < T_N; ++nj) {
      int off = (wc * SN + nj * 16) * 64 + fo;
      bh[nj] = *(const short8x*)((const char*)sBh + off);
      bl[nj] = *(const short8x*)((const char*)sBl + off);
    }
    #pragma unroll
    for (int mi = 0; mi < T_M; ++mi)
      #pragma unroll
      for (int nj = 0; nj < T_N; ++nj) {
        acc[mi][nj] = __builtin_amdgcn_mfma_f32_16x16x32_bf16(ah[mi], bh[nj], acc[mi][nj], 0, 0, 0);
        acc[mi][nj] = __builtin_amdgcn_mfma_f32_16x16x32_bf16(ah[mi], bl[nj], acc[mi][nj], 0, 0, 0);
        acc[mi][nj] = __builtin_amdgcn_mfma_f32_16x16x32_bf16(al[mi], bh[nj], acc[mi][nj], 0, 0, 0);
      }
  }

  // epilogue — C/D layout: col = lane&15, row = (lane>>4)*4 + reg
  const int cl = lane & 15, qd = lane >> 4;
  const int colbase = bn + wc * SN;
  const int rowbase = bm + wr * SM;
  if (EPI == 1) {
    #pragma unroll
    for (int mi = 0; mi < T_M; ++mi) {
      int r0 = rowbase + mi * 16 + qd * 4;
      #pragma unroll
      for (int nj = 0; nj < T_N; ++nj) {
        int col = colbase + nj * 16 + cl;
        float bv = bias[col];
        #pragma unroll
        for (int rg = 0; rg < 4; ++rg)
          C[(size_t)(r0 + rg) * ldc + col] = acc[mi][nj][rg] + bv;
      }
    }
  } else if (EPI == 4) {
    #pragma unroll
    for (int mi = 0; mi < T_M; ++mi) {
      int m = rowbase + mi * 16 + qd * 4;
      int b = m >> 9, l = m & 511;
      #pragma unroll
      for (int nj = 0; nj < T_N; ++nj) {
        int col = colbase + nj * 16 + cl;
        float bv = bias[col];
        float4 v;
        v.x = softplusf(acc[mi][nj][0] + bv);
        v.y = softplusf(acc[mi][nj][1] + bv);
        v.z = softplusf(acc[mi][nj][2] + bv);
        v.w = softplusf(acc[mi][nj][3] + bv);
        *reinterpret_cast<float4*>(&C[((size_t)b * DIN + col) * LSEQ + l]) = v;
      }
    }
  } else if (EPI == 5) {
    if (bn < 1536) {
      #pragma unroll
      for (int mi = 0; mi < T_M; ++mi) {
        int r0 = rowbase + mi * 16 + qd * 4;
        #pragma unroll
        for (int nj = 0; nj < T_N; ++nj) {
          int col = colbase + nj * 16 + cl;
          #pragma unroll
          for (int rg = 0; rg < 4; ++rg)
            C[(size_t)(r0 + rg) * ldc + col] = acc[mi][nj][rg];
        }
      }
    } else {
      #pragma unroll
      for (int mi = 0; mi < T_M; ++mi) {
        int m = rowbase + mi * 16 + qd * 4;
        int b = m >> 9, l = m & 511;
        #pragma unroll
        for (int nj = 0; nj < T_N; ++nj) {
          int colz = colbase - 1536 + nj * 16 + cl;
          float4 v;
          v.x = acc[mi][nj][0]; v.y = acc[mi][nj][1];
          v.z = acc[mi][nj][2]; v.w = acc[mi][nj][3];
          *reinterpret_cast<float4*>(&C2[((size_t)b * DIN + colz) * LSEQ + l]) = v;
        }
      }
    }
  } else if (EPI == 6) {
    #pragma unroll
    for (int mi = 0; mi < T_M; ++mi) {
      int r0 = rowbase + mi * 16 + qd * 4;
      #pragma unroll
      for (int nj = 0; nj < T_N; ++nj) {
        int col = colbase + nj * 16 + cl;
        #pragma unroll
        for (int rg = 0; rg < 4; ++rg) {
          float v = acc[mi][nj][rg];
          C[(size_t)(r0 + rg) * 192 + col] = v;
          if (col < 64) {
            bf16 h, l;
            if (col < 48) bsplit(v, h, l);
            else { h = __float2bfloat16(0.f); l = h; }
            Oh[(size_t)(r0 + rg) * 64 + col] = h;
            Ol[(size_t)(r0 + rg) * 64 + col] = l;
          }
        }
      }
    }
  }
}

// ---------------------------------------------------------------------------
// Fused prep: modality hi/lo splits (blocks 0..36863) + all 4 weight
// transposes+splits (blocks 36864..37967).
__global__ __launch_bounds__(256) void prep_k(
    const float* __restrict__ s0, const float* __restrict__ s1,
    const float* __restrict__ s2, bf16* __restrict__ moddst,
    const float* __restrict__ pw, const float* __restrict__ ipw,
    const float* __restrict__ xpw, const float* __restrict__ dtw,
    bf16* pwTh, bf16* pwTl, bf16* ipTh, bf16* ipTl,
    bf16* xpTh, bf16* xpTl, bf16* dtTh, bf16* dtTl)
{
  __shared__ float T[64][65];
  const int tid = threadIdx.x;
  if (blockIdx.x < 36864) {
    const int per = 4096 * 768 / 256;
    int seg = blockIdx.x / per;
    int idx = (blockIdx.x - seg * per) * 256 + tid;
    const float* src = (seg == 0) ? s0 : (seg == 1) ? s1 : s2;
    bf16* hi = moddst + (size_t)seg * 2 * 4096 * 768;
    bf16* lo = hi + (size_t)4096 * 768;
    bf16 h, l; bsplit(src[idx], h, l);
    hi[idx] = h; lo[idx] = l;
    return;
  }
  const int id = blockIdx.x - 36864;
  const float* src; bf16 *hi, *lo; int P, Q, ld, Ppad, px, qx;
  if (id < 432)       { src = pw;  hi = pwTh; lo = pwTl; P = 2304; Q = 768;  ld = 768;  Ppad = 2304; px = id % 36;          qx = id / 36; }
  else if (id < 1008) { int i = id - 432;  src = ipw; hi = ipTh; lo = ipTl; P = 768;  Q = 3072; ld = 3072; Ppad = 768;  px = i % 12; qx = i / 12; }
  else if (id < 1080) { int i = id - 1008; src = xpw; hi = xpTh; lo = xpTl; P = 1536; Q = 176;  ld = 176;  Ppad = 1536; px = i % 24; qx = i / 24; }
  else                { int i = id - 1080; src = dtw; hi = dtTh; lo = dtTl; P = 48;   Q = 1536; ld = 1536; Ppad = 64;   px = 0;      qx = i; }
  const int p0 = px * 64, q0 = qx * 64;
  {
    int j = tid & 63, i0 = tid >> 6;
    for (int i = i0; i < 64; i += 4) {
      int p = p0 + i, q = q0 + j;
      T[i][j] = (p < P && q < Q) ? src[(size_t)p * ld + q] : 0.f;
    }
  }
  __syncthreads();
  {
    int ii = tid & 63, j0 = tid >> 6;
    for (int jj = j0; jj < 64; jj += 4) {
      bf16 h, l; bsplit(T[ii][jj], h, l);
      size_t o = (size_t)(q0 + jj) * Ppad + p0 + ii;
      hi[o] = h; lo[o] = l;
    }
  }
}

// ---------------------------------------------------------------------------
__device__ inline float block_sum256(float s, float* red) {
  #pragma unroll
  for (int o = 32; o > 0; o >>= 1) s += __shfl_xor(s, o, 64);
  int tid = threadIdx.x;
  __syncthreads();
  if ((tid & 63) == 0) red[tid >> 6] = s;
  __syncthreads();
  return red[0] + red[1] + red[2] + red[3];
}

__global__ __launch_bounds__(256) void ln2_k(
    const float* __restrict__ pre,
    const float* __restrict__ g1, const float* __restrict__ b1,
    const float* __restrict__ g2, const float* __restrict__ b2,
    float* __restrict__ fused, bf16* __restrict__ hAh, bf16* __restrict__ hAl)
{
  __shared__ float red[4];
  const int row = blockIdx.x;
  const int tid = threadIdx.x;
  const float* x = pre + (size_t)row * 768;
  float v0 = x[tid], v1 = x[tid + 256], v2 = x[tid + 512];

  float mu = block_sum256(v0 + v1 + v2, red) * (1.f / 768.f);
  float c0 = v0 - mu, c1 = v1 - mu, c2 = v2 - mu;
  float var = block_sum256(c0*c0 + c1*c1 + c2*c2, red) * (1.f / 768.f);
  float r = rsqrtf(var + 1e-5f);
  float f0 = c0 * r * g1[tid] + b1[tid];
  float f1 = c1 * r * g1[tid + 256] + b1[tid + 256];
  float f2 = c2 * r * g1[tid + 512] + b1[tid + 512];
  float* fo = fused + (size_t)row * 768;
  fo[tid] = f0; fo[tid + 256] = f1; fo[tid + 512] = f2;

  float mu2 = block_sum256(f0 + f1 + f2, red) * (1.f / 768.f);
  float d0 = f0 - mu2, d1 = f1 - mu2, d2 = f2 - mu2;
  float var2 = block_sum256(d0*d0 + d1*d1 + d2*d2, red) * (1.f / 768.f);
  float r2 = rsqrtf(var2 + 1e-5f);
  float h0 = d0 * r2 * g2[tid] + b2[tid];
  float h1 = d1 * r2 * g2[tid + 256] + b2[tid + 256];
  float h2 = d2 * r2 * g2[tid + 512] + b2[tid + 512];
  bf16 hh, hl;
  size_t o = (size_t)row * 768;
  bsplit(h0, hh, hl); hAh[o + tid] = hh; hAl[o + tid] = hl;
  bsplit(h1, hh, hl); hAh[o + tid + 256] = hh; hAl[o + tid + 256] = hl;
  bsplit(h2, hh, hl); hAh[o + tid + 512] = hh; hAl[o + tid + 512] = hl;
}

// Causal depthwise conv (K=4) + bias + silu.
// Outputs xct [B][DIN][L] fp32 (scan) AND xcA [row][DIN] bf16 hi/lo (x_proj A).
__global__ __launch_bounds__(256) void conv2x_k(
    const float* __restrict__ xbuf, const float* __restrict__ w,
    const float* __restrict__ cb, float* __restrict__ xct,
    bf16* __restrict__ xcAh, bf16* __restrict__ xcAl)
{
  __shared__ float Xs[67][65];
  __shared__ float Ys[64][65];
  const int tid = threadIdx.x;
  const int l0 = blockIdx.x * 64;
  const int d0 = blockIdx.y * 64;
  const int b  = blockIdx.z;
  for (int e = tid; e < 67 * 64; e += 256) {
    int r = e >> 6, dd = e & 63;
    int l = l0 - 3 + r;
    Xs[r][dd] = (l >= 0) ? xbuf[((size_t)b * 512 + l) * DIN + d0 + dd] : 0.f;
  }
  __syncthreads();
  {
    const int lane = tid & 63, grp = tid >> 6;
    #pragma unroll
    for (int i = 0; i < 16; ++i) {
      int dd = grp + i * 4;
      int d = d0 + dd;
      float acc = cb[d];
      #pragma unroll
      for (int k = 0; k < 4; ++k)
        acc = fmaf(Xs[lane + k][dd], w[d * 4 + k], acc);
      float v = acc / (1.f + __expf(-acc));
      xct[((size_t)b * DIN + d) * LSEQ + l0 + lane] = v;
      Ys[lane][dd] = v;
    }
  }
  __syncthreads();
  {
    const int dd = tid & 63, lg = tid >> 6;
    #pragma unroll
    for (int j = 0; j < 16; ++j) {
      int l = lg * 16 + j;
      bf16 h, lo; bsplit(Ys[l][dd], h, lo);
      size_t o = (size_t)(b * 512 + l0 + l) * DIN + d0 + dd;
      xcAh[o] = h; xcAl[o] = lo;
    }
  }
}

// Selective scan v5: 4 waves/block share b; wave -> d; lane -> state n.
// Per step: 1 broadcast ds_read_b64 (dt,du) + 1 ds_read_b64 (B,C) + mul/exp/
// mul/fma/mul + 2 quad-DPP adds + predicated ds_write of 16 quad partials.
// Per 64-step chunk: lane t sums its 16 partials from LDS (stride 17,
// conflict-free) -> y lands directly at lane == t (no select, no readlane).
__global__ __launch_bounds__(256) void scan5_k(
    const float* __restrict__ delta_t, const float* __restrict__ xct,
    const float* __restrict__ dbl, const float* __restrict__ zt,
    const float* __restrict__ A_log, const float* __restrict__ Dv,
    float* __restrict__ ysbar)
{
  __shared__ float BC[64][128];      // [t][2n+{0,1}] = {B,C}   32 KB (block-shared)
  __shared__ float DT[4][64][2];     // [wv][t][{dt,du}]         2 KB
  __shared__ float Pq[4][64][17];    // [wv][t][quad] partials  17 KB (16 used +pad)
  const int tid = threadIdx.x;
  const int lane = tid & 63;
  const int wv = tid >> 6;
  const int bid = blockIdx.x;        // 3072 = 8 * 384
  const int b = bid / 384;
  const int d = (bid - b * 384) * 4 + wv;
  const float Ad2 = -__expf(A_log[d * 64 + lane]) * 1.442695041f;  // exp2 scale
  const float Dd = Dv[d];
  const size_t strm = ((size_t)b * DIN + d) * LSEQ;
  float h = 0.f, ysum = 0.f;

  for (int l0 = 0; l0 < LSEQ; l0 += 64) {
    __syncthreads();
    #pragma unroll
    for (int i = 0; i < 16; ++i) {
      int t = wv * 16 + i;
      const float* src = dbl + (size_t)(b * LSEQ + l0 + t) * 192;
      float2 v; v.x = src[48 + lane]; v.y = src[112 + lane];
      *reinterpret_cast<float2*>(&BC[t][lane * 2]) = v;
    }
    float dt_v = delta_t[strm + l0 + lane];
    float u_v  = xct[strm + l0 + lane];
    float z_v  = zt[strm + l0 + lane];
    float2 dd; dd.x = dt_v; dd.y = dt_v * u_v;
    *reinterpret_cast<float2*>(&DT[wv][lane][0]) = dd;
    __syncthreads();

    #pragma unroll
    for (int t = 0; t < 64; ++t) {
      float2 sd = *reinterpret_cast<const float2*>(&DT[wv][t][0]);   // broadcast
      float2 bc = *reinterpret_cast<const float2*>(&BC[t][lane * 2]);
      float e = exp2f(sd.x * Ad2);
      h = fmaf(e, h, sd.y * bc.x);
      float p = h * bc.y;
      p = dpp_add<0x111>(p);   // row_shr:1
      p = dpp_add<0x112>(p);   // row_shr:2 -> lane 4k+3 holds quad sum
      if ((lane & 3) == 3) Pq[wv][t][lane >> 2] = p;
    }
    // lane = t sums its 16 quad partials (same wave wrote them; lgkm dep only)
    float yk = 0.f;
    #pragma unroll
    for (int j = 0; j < 16; ++j) yk += Pq[wv][lane][j];
    float yv = (yk + u_v * Dd) * (z_v / (1.f + __expf(-z_v)));
    ysum += yv;
  }
  float tot = readlane_f(dpp_wave_sum(ysum), 63);
  if (lane == 0) ysbar[b * 1536 + d] = tot;
}

// out[b][c] = (sum_l fused[b,l,c] + sum_d ysbar[b,d]*W[d,c]) / 512
__global__ __launch_bounds__(256) void final_k(
    const float* __restrict__ fused, const float* __restrict__ ysbar,
    const float* __restrict__ W, float* __restrict__ out)
{
  __shared__ float ys[1536];
  const int b = blockIdx.y;
  const int c = blockIdx.x * 256 + threadIdx.x;
  for (int i = threadIdx.x; i < 1536; i += 256) ys[i] = ysbar[b * 1536 + i];
  __syncthreads();
  float sf = 0.f;
  for (int l = 0; l < 512; ++l) sf += fused[(size_t)((b << 9) + l) * 768 + c];
  float dot = 0.f;
  for (int d = 0; d < 1536; ++d) dot = fmaf(ys[d], W[(size_t)d * 768 + c], dot);
  out[b * 768 + c] = (sf + dot) * (1.f / 512.f);
}

// ---------------------------------------------------------------------------
extern "C" void kernel_launch(void* const* d_in, const int* in_sizes, int n_in,
                              void* d_out, int out_size, void* d_ws, size_t ws_size,
                              hipStream_t stream)
{
  const float* text      = (const float*)d_in[0];
  const float* audio     = (const float*)d_in[1];
  const float* video     = (const float*)d_in[2];
  const float* proj_w    = (const float*)d_in[3];
  const float* proj_b    = (const float*)d_in[4];
  const float* proj_ln_g = (const float*)d_in[5];
  const float* proj_ln_b = (const float*)d_in[6];
  const float* blk_ln_g  = (const float*)d_in[7];
  const float* blk_ln_b  = (const float*)d_in[8];
  const float* in_proj_w = (const float*)d_in[9];
  const float* conv_w    = (const float*)d_in[10];
  const float* conv_b    = (const float*)d_in[11];
  const float* x_proj_w  = (const float*)d_in[12];
  const float* dt_proj_w = (const float*)d_in[13];
  const float* dt_proj_b = (const float*)d_in[14];
  const float* A_log     = (const float*)d_in[15];
  const float* Dv        = (const float*)d_in[16];
  const float* out_projw = (const float*)d_in[17];
  float* out = (float*)d_out;

  // ---- workspace arena ----
  char* p = (char*)d_ws;
  const size_t P768 = (size_t)4096 * 768 * 2;     // one bf16 [4096][768]
  char* S1 = p; p += 6 * P768;                    // modality splits -> hA -> xcA
  char* SW = p; p += 18087936;                    // weights
  char* S3 = p; p += (size_t)4096 * 768 * 4;      // pre
  char* S4 = p; p += (size_t)4096 * 768 * 4;      // fused
  char* S6 = p; p += (size_t)4096 * 1536 * 4;     // xbuf -> delta_t
  char* S7 = p; p += (size_t)4096 * 1536 * 4;     // zt
  char* S8 = p; p += (size_t)4096 * 1536 * 4;     // xct
  char* SD = p; p += (size_t)4096 * 64 * 4;       // dtA hi/lo
  char* S9 = p; p += (size_t)4096 * 192 * 4;      // dbl
  char* SY = p; p += 12288 * 4;                   // ysbar

  bf16* modspl = (bf16*)S1;
  bf16 *tAh = (bf16*)S1,              *tAl = (bf16*)(S1 + P768);
  bf16 *aAh = (bf16*)(S1 + 2 * P768), *aAl = (bf16*)(S1 + 3 * P768);
  bf16 *vAh = (bf16*)(S1 + 4 * P768), *vAl = (bf16*)(S1 + 5 * P768);
  bf16 *hAh = (bf16*)S1,              *hAl = (bf16*)(S1 + P768);
  bf16 *xcAh = (bf16*)S1,             *xcAl = (bf16*)(S1 + (size_t)4096 * 1536 * 2);
  bf16 *pwTh = (bf16*)SW,                    *pwTl = pwTh + (size_t)768 * 2304;
  bf16 *ipTh = pwTl + (size_t)768 * 2304,    *ipTl = ipTh + (size_t)3072 * 768;
  bf16 *xpTh = ipTl + (size_t)3072 * 768,    *xpTl = xpTh + (size_t)192 * 1536;
  bf16 *dtTh = xpTl + (size_t)192 * 1536,    *dtTl = dtTh + (size_t)1536 * 64;
  float* pre     = (float*)S3;
  float* fused   = (float*)S4;
  float* xbuf    = (float*)S6;  float* delta_t = (float*)S6;
  float* zt      = (float*)S7;
  float* xct     = (float*)S8;
  bf16 *dtAh = (bf16*)SD, *dtAl = (bf16*)(SD + (size_t)4096 * 64 * 2);
  float* dbl     = (float*)S9;
  float* ysbar   = (float*)SY;

  // 1) all prep (modality splits + weight transposes) in one launch
  prep_k<<<37968, 256, 0, stream>>>(text, audio, video, modspl,
                                    proj_w, in_proj_w, x_proj_w, dt_proj_w,
                                    pwTh, pwTl, ipTh, ipTl, xpTh, xpTl, dtTh, dtTl);
  // 2) pre = concat @ proj_w + proj_b
  mgemm<128, 64, 4, 2, 1, 1><<<dim3(32, 12), 512, 0, stream>>>(
      tAh, tAl, aAh, aAl, vAh, vAl, pwTh, pwTl, proj_b,
      pre, nullptr, nullptr, nullptr, 2304, 768, 768);
  // 3) fused = LN1(pre); hA = split(LN2(fused))
  ln2_k<<<4096, 256, 0, stream>>>(pre, proj_ln_g, proj_ln_b, blk_ln_g, blk_ln_b, fused, hAh, hAl);
  // 4) [x|z] = h @ in_proj_w: x -> xbuf [4096][1536], z -> zt [B][DIN][L]
  mgemm<128, 128, 2, 2, 0, 5><<<dim3(32, 24), 256, 0, stream>>>(
      hAh, hAl, nullptr, nullptr, nullptr, nullptr, ipTh, ipTl, nullptr,
      xbuf, zt, nullptr, nullptr, 768, 768, 1536);
  // 5) xct = silu(dwconv(x)+cb) transposed; xcA = split(xct) row-major
  conv2x_k<<<dim3(8, 24, 8), 256, 0, stream>>>(xbuf, conv_w, conv_b, xct, xcAh, xcAl);
  // 6) dbl = xconv @ x_proj_w [4096][192] fp32 + dtA hi/lo (cols<48, pad 64)
  mgemm<64, 64, 4, 2, 0, 6><<<dim3(64, 3), 512, 0, stream>>>(
      xcAh, xcAl, nullptr, nullptr, nullptr, nullptr, xpTh, xpTl, nullptr,
      dbl, nullptr, dtAh, dtAl, 1536, 1536, 192);
  // 7) delta_t = softplus(dt @ dt_proj_w + b) transposed [B][DIN][L]
  mgemm<128, 64, 4, 2, 0, 4><<<dim3(32, 24), 512, 0, stream>>>(
      dtAh, dtAl, nullptr, nullptr, nullptr, nullptr, dtTh, dtTl, dt_proj_b,
      delta_t, nullptr, nullptr, nullptr, 64, 64, 0);
  // 8) selective scan -> ysbar[b][d] = sum_l y
  scan5_k<<<3072, 256, 0, stream>>>(delta_t, xct, dbl, zt, A_log, Dv, ysbar);
  // 9) out = (sum_l fused + ysbar @ out_proj_w) / 512
  final_k<<<dim3(3, 8), 256, 0, stream>>>(fused, ysbar, out_projw, out);
}

// Round 8
// 615.796 us; speedup vs baseline: 3.8971x; 1.0778x over previous
//
#include <hip/hip_runtime.h>
#include <hip/hip_bf16.h>
#include <cstddef>
#include <cstdint>

// B=8, L=512, H=768, DIN=1536, N=64, R=48, Kc=4. M = B*L = 4096.
#define DIN 1536
#define LSEQ 512

typedef __hip_bfloat16 bf16;
typedef __attribute__((ext_vector_type(8))) short short8x;
typedef __attribute__((ext_vector_type(4))) float f32x4;
typedef const __attribute__((address_space(1))) unsigned int* gp1;
typedef __attribute__((address_space(3))) unsigned int* lp3;

__device__ inline float readlane_f(float v, int l) {
  return __uint_as_float(__builtin_amdgcn_readlane(__float_as_uint(v), l));
}
__device__ inline void gload_lds(const bf16* g, unsigned short* l) {
  __builtin_amdgcn_global_load_lds((gp1)g, (lp3)l, 16, 0, 0);
}
__device__ inline void bsplit(float v, bf16& h, bf16& l) {
  h = __float2bfloat16(v);
  l = __float2bfloat16(v - __bfloat162float(h));
}
__device__ inline float softplusf(float t) {
  return fmaxf(t, 0.f) + log1pf(__expf(-fabsf(t)));
}
template<int CTRL>
__device__ inline float dpp_add(float v) {
  int t = __builtin_amdgcn_update_dpp(0, __float_as_int(v), CTRL, 0xf, 0xf, true);
  return v + __int_as_float(t);
}
// full-wave sum -> result valid in lane 63
__device__ inline float dpp_wave_sum(float p) {
  p = dpp_add<0x111>(p);  // row_shr:1
  p = dpp_add<0x112>(p);  // row_shr:2
  p = dpp_add<0x114>(p);  // row_shr:4
  p = dpp_add<0x118>(p);  // row_shr:8
  p = dpp_add<0x142>(p);  // row_bcast:15
  p = dpp_add<0x143>(p);  // row_bcast:31
  return p;
}

// ---------------------------------------------------------------------------
// bf16x3 MFMA GEMM. C = A*B fp32-accurate via hi/lo bf16 split (3 MFMA passes).
// A: [M][K] bf16 hi/lo (AMODE 1: concat of 3 segments of 768 along k).
// B: [N][K] bf16 hi/lo (transposed weights).
// EPI 1: C = acc + bias[col]
// EPI 4: softplus(acc+bias[col]) -> transposed [b][col][l]
// EPI 5: col<1536 -> C[row*ldc+col]; else acc -> C2 transposed [b][col-1536][l]
// EPI 6: C[row*192+col] = acc (fp32); col<64 -> Oh/Ol[row*64+col] = split(acc)
// ---------------------------------------------------------------------------
template<int TBM, int TBN, int WR, int WC, int AMODE, int EPI>
__global__ __launch_bounds__(WR*WC*64) void mgemm(
    const bf16* __restrict__ Ah0, const bf16* __restrict__ Al0,
    const bf16* __restrict__ Ah1, const bf16* __restrict__ Al1,
    const bf16* __restrict__ Ah2, const bf16* __restrict__ Al2,
    const bf16* __restrict__ Bh, const bf16* __restrict__ Bl,
    const float* __restrict__ bias,
    float* __restrict__ C, float* __restrict__ C2,
    bf16* __restrict__ Oh, bf16* __restrict__ Ol,
    int K, int lda, int ldc)
{
  constexpr int NW = WR * WC;
  constexpr int SM = TBM / WR, SN = TBN / WC;
  constexpr int T_M = SM / 16, T_N = SN / 16;
  __shared__ unsigned short sAh[TBM * 32], sAl[TBM * 32];
  __shared__ unsigned short sBh[TBN * 32], sBl[TBN * 32];
  const int tid = threadIdx.x;
  const int lane = tid & 63, wid = tid >> 6;
  const int bm = blockIdx.x * TBM, bn = blockIdx.y * TBN;
  const int wr = wid / WC, wc = wid % WC;

  const int stg_m = lane >> 2;
  const int stg_k = ((lane & 3) ^ ((lane >> 3) & 3)) * 8;
  const int fo = (lane & 15) * 64 + ((((lane >> 4) ^ ((lane >> 1) & 3)) & 3) * 16);

  f32x4 acc[T_M][T_N];
  #pragma unroll
  for (int i = 0; i < T_M; ++i)
    #pragma unroll
    for (int j = 0; j < T_N; ++j) acc[i][j] = (f32x4){0.f, 0.f, 0.f, 0.f};

  for (int k0 = 0; k0 < K; k0 += 32) {
    __syncthreads();
    const bf16* pAh; const bf16* pAl; int ka;
    if (AMODE == 1) {
      int seg = k0 / 768;
      pAh = (seg == 0) ? Ah0 : (seg == 1) ? Ah1 : Ah2;
      pAl = (seg == 0) ? Al0 : (seg == 1) ? Al1 : Al2;
      ka = k0 - seg * 768;
    } else { pAh = Ah0; pAl = Al0; ka = k0; }
    #pragma unroll
    for (int q = wid; q < TBM / 16; q += NW) {
      size_t go = (size_t)(bm + q * 16 + stg_m) * lda + ka + stg_k;
      gload_lds(pAh + go, &sAh[q * 512]);
      gload_lds(pAl + go, &sAl[q * 512]);
    }
    #pragma unroll
    for (int q = wid; q < TBN / 16; q += NW) {
      size_t go = (size_t)(bn + q * 16 + stg_m) * K + k0 + stg_k;
      gload_lds(Bh + go, &sBh[q * 512]);
      gload_lds(Bl + go, &sBl[q * 512]);
    }
    __syncthreads();

    short8x ah[T_M], al[T_M], bh[T_N], bl[T_N];
    #pragma unroll
    for (int mi = 0; mi < T_M; ++mi) {
      int off = (wr * SM + mi * 16) * 64 + fo;
      ah[mi] = *(const short8x*)((const char*)sAh + off);
      al[mi] = *(const short8x*)((const char*)sAl + off);
    }
    #pragma unroll
    for (int nj = 0; nj < T_N; ++nj) {
      int off = (wc * SN + nj * 16) * 64 + fo;
      bh[nj] = *(const short8x*)((const char*)sBh + off);
      bl[nj] = *(const short8x*)((const char*)sBl + off);
    }
    #pragma unroll
    for (int mi = 0; mi < T_M; ++mi)
      #pragma unroll
      for (int nj = 0; nj < T_N; ++nj) {
        acc[mi][nj] = __builtin_amdgcn_mfma_f32_16x16x32_bf16(ah[mi], bh[nj], acc[mi][nj], 0, 0, 0);
        acc[mi][nj] = __builtin_amdgcn_mfma_f32_16x16x32_bf16(ah[mi], bl[nj], acc[mi][nj], 0, 0, 0);
        acc[mi][nj] = __builtin_amdgcn_mfma_f32_16x16x32_bf16(al[mi], bh[nj], acc[mi][nj], 0, 0, 0);
      }
  }

  // epilogue — C/D layout: col = lane&15, row = (lane>>4)*4 + reg
  const int cl = lane & 15, qd = lane >> 4;
  const int colbase = bn + wc * SN;
  const int rowbase = bm + wr * SM;
  if (EPI == 1) {
    #pragma unroll
    for (int mi = 0; mi < T_M; ++mi) {
      int r0 = rowbase + mi * 16 + qd * 4;
      #pragma unroll
      for (int nj = 0; nj < T_N; ++nj) {
        int col = colbase + nj * 16 + cl;
        float bv = bias[col];
        #pragma unroll
        for (int rg = 0; rg < 4; ++rg)
          C[(size_t)(r0 + rg) * ldc + col] = acc[mi][nj][rg] + bv;
      }
    }
  } else if (EPI == 4) {
    #pragma unroll
    for (int mi = 0; mi < T_M; ++mi) {
      int m = rowbase + mi * 16 + qd * 4;
      int b = m >> 9, l = m & 511;
      #pragma unroll
      for (int nj = 0; nj < T_N; ++nj) {
        int col = colbase + nj * 16 + cl;
        float bv = bias[col];
        float4 v;
        v.x = softplusf(acc[mi][nj][0] + bv);
        v.y = softplusf(acc[mi][nj][1] + bv);
        v.z = softplusf(acc[mi][nj][2] + bv);
        v.w = softplusf(acc[mi][nj][3] + bv);
        *reinterpret_cast<float4*>(&C[((size_t)b * DIN + col) * LSEQ + l]) = v;
      }
    }
  } else if (EPI == 5) {
    if (bn < 1536) {
      #pragma unroll
      for (int mi = 0; mi < T_M; ++mi) {
        int r0 = rowbase + mi * 16 + qd * 4;
        #pragma unroll
        for (int nj = 0; nj < T_N; ++nj) {
          int col = colbase + nj * 16 + cl;
          #pragma unroll
          for (int rg = 0; rg < 4; ++rg)
            C[(size_t)(r0 + rg) * ldc + col] = acc[mi][nj][rg];
        }
      }
    } else {
      #pragma unroll
      for (int mi = 0; mi < T_M; ++mi) {
        int m = rowbase + mi * 16 + qd * 4;
        int b = m >> 9, l = m & 511;
        #pragma unroll
        for (int nj = 0; nj < T_N; ++nj) {
          int colz = colbase - 1536 + nj * 16 + cl;
          float4 v;
          v.x = acc[mi][nj][0]; v.y = acc[mi][nj][1];
          v.z = acc[mi][nj][2]; v.w = acc[mi][nj][3];
          *reinterpret_cast<float4*>(&C2[((size_t)b * DIN + colz) * LSEQ + l]) = v;
        }
      }
    }
  } else if (EPI == 6) {
    #pragma unroll
    for (int mi = 0; mi < T_M; ++mi) {
      int r0 = rowbase + mi * 16 + qd * 4;
      #pragma unroll
      for (int nj = 0; nj < T_N; ++nj) {
        int col = colbase + nj * 16 + cl;
        #pragma unroll
        for (int rg = 0; rg < 4; ++rg) {
          float v = acc[mi][nj][rg];
          C[(size_t)(r0 + rg) * 192 + col] = v;
          if (col < 64) {
            bf16 h, l;
            if (col < 48) bsplit(v, h, l);
            else { h = __float2bfloat16(0.f); l = h; }
            Oh[(size_t)(r0 + rg) * 64 + col] = h;
            Ol[(size_t)(r0 + rg) * 64 + col] = l;
          }
        }
      }
    }
  }
}

// ---------------------------------------------------------------------------
// Fused prep: modality hi/lo splits (blocks 0..36863) + all 4 weight
// transposes+splits (blocks 36864..37967).
__global__ __launch_bounds__(256) void prep_k(
    const float* __restrict__ s0, const float* __restrict__ s1,
    const float* __restrict__ s2, bf16* __restrict__ moddst,
    const float* __restrict__ pw, const float* __restrict__ ipw,
    const float* __restrict__ xpw, const float* __restrict__ dtw,
    bf16* pwTh, bf16* pwTl, bf16* ipTh, bf16* ipTl,
    bf16* xpTh, bf16* xpTl, bf16* dtTh, bf16* dtTl)
{
  __shared__ float T[64][65];
  const int tid = threadIdx.x;
  if (blockIdx.x < 36864) {
    const int per = 4096 * 768 / 256;
    int seg = blockIdx.x / per;
    int idx = (blockIdx.x - seg * per) * 256 + tid;
    const float* src = (seg == 0) ? s0 : (seg == 1) ? s1 : s2;
    bf16* hi = moddst + (size_t)seg * 2 * 4096 * 768;
    bf16* lo = hi + (size_t)4096 * 768;
    bf16 h, l; bsplit(src[idx], h, l);
    hi[idx] = h; lo[idx] = l;
    return;
  }
  const int id = blockIdx.x - 36864;
  const float* src; bf16 *hi, *lo; int P, Q, ld, Ppad, px, qx;
  if (id < 432)       { src = pw;  hi = pwTh; lo = pwTl; P = 2304; Q = 768;  ld = 768;  Ppad = 2304; px = id % 36;          qx = id / 36; }
  else if (id < 1008) { int i = id - 432;  src = ipw; hi = ipTh; lo = ipTl; P = 768;  Q = 3072; ld = 3072; Ppad = 768;  px = i % 12; qx = i / 12; }
  else if (id < 1080) { int i = id - 1008; src = xpw; hi = xpTh; lo = xpTl; P = 1536; Q = 176;  ld = 176;  Ppad = 1536; px = i % 24; qx = i / 24; }
  else                { int i = id - 1080; src = dtw; hi = dtTh; lo = dtTl; P = 48;   Q = 1536; ld = 1536; Ppad = 64;   px = 0;      qx = i; }
  const int p0 = px * 64, q0 = qx * 64;
  {
    int j = tid & 63, i0 = tid >> 6;
    for (int i = i0; i < 64; i += 4) {
      int p = p0 + i, q = q0 + j;
      T[i][j] = (p < P && q < Q) ? src[(size_t)p * ld + q] : 0.f;
    }
  }
  __syncthreads();
  {
    int ii = tid & 63, j0 = tid >> 6;
    for (int jj = j0; jj < 64; jj += 4) {
      bf16 h, l; bsplit(T[ii][jj], h, l);
      size_t o = (size_t)(q0 + jj) * Ppad + p0 + ii;
      hi[o] = h; lo[o] = l;
    }
  }
}

// ---------------------------------------------------------------------------
__device__ inline float block_sum256(float s, float* red) {
  #pragma unroll
  for (int o = 32; o > 0; o >>= 1) s += __shfl_xor(s, o, 64);
  int tid = threadIdx.x;
  __syncthreads();
  if ((tid & 63) == 0) red[tid >> 6] = s;
  __syncthreads();
  return red[0] + red[1] + red[2] + red[3];
}

__global__ __launch_bounds__(256) void ln2_k(
    const float* __restrict__ pre,
    const float* __restrict__ g1, const float* __restrict__ b1,
    const float* __restrict__ g2, const float* __restrict__ b2,
    float* __restrict__ fused, bf16* __restrict__ hAh, bf16* __restrict__ hAl)
{
  __shared__ float red[4];
  const int row = blockIdx.x;
  const int tid = threadIdx.x;
  const float* x = pre + (size_t)row * 768;
  float v0 = x[tid], v1 = x[tid + 256], v2 = x[tid + 512];

  float mu = block_sum256(v0 + v1 + v2, red) * (1.f / 768.f);
  float c0 = v0 - mu, c1 = v1 - mu, c2 = v2 - mu;
  float var = block_sum256(c0*c0 + c1*c1 + c2*c2, red) * (1.f / 768.f);
  float r = rsqrtf(var + 1e-5f);
  float f0 = c0 * r * g1[tid] + b1[tid];
  float f1 = c1 * r * g1[tid + 256] + b1[tid + 256];
  float f2 = c2 * r * g1[tid + 512] + b1[tid + 512];
  float* fo = fused + (size_t)row * 768;
  fo[tid] = f0; fo[tid + 256] = f1; fo[tid + 512] = f2;

  float mu2 = block_sum256(f0 + f1 + f2, red) * (1.f / 768.f);
  float d0 = f0 - mu2, d1 = f1 - mu2, d2 = f2 - mu2;
  float var2 = block_sum256(d0*d0 + d1*d1 + d2*d2, red) * (1.f / 768.f);
  float r2 = rsqrtf(var2 + 1e-5f);
  float h0 = d0 * r2 * g2[tid] + b2[tid];
  float h1 = d1 * r2 * g2[tid + 256] + b2[tid + 256];
  float h2 = d2 * r2 * g2[tid + 512] + b2[tid + 512];
  bf16 hh, hl;
  size_t o = (size_t)row * 768;
  bsplit(h0, hh, hl); hAh[o + tid] = hh; hAl[o + tid] = hl;
  bsplit(h1, hh, hl); hAh[o + tid + 256] = hh; hAl[o + tid + 256] = hl;
  bsplit(h2, hh, hl); hAh[o + tid + 512] = hh; hAl[o + tid + 512] = hl;
}

// Causal depthwise conv (K=4) + bias + silu.
// Outputs xct [B][DIN][L] fp32 (scan) AND xcA [row][DIN] bf16 hi/lo (x_proj A).
__global__ __launch_bounds__(256) void conv2x_k(
    const float* __restrict__ xbuf, const float* __restrict__ w,
    const float* __restrict__ cb, float* __restrict__ xct,
    bf16* __restrict__ xcAh, bf16* __restrict__ xcAl)
{
  __shared__ float Xs[67][65];
  __shared__ float Ys[64][65];
  const int tid = threadIdx.x;
  const int l0 = blockIdx.x * 64;
  const int d0 = blockIdx.y * 64;
  const int b  = blockIdx.z;
  for (int e = tid; e < 67 * 64; e += 256) {
    int r = e >> 6, dd = e & 63;
    int l = l0 - 3 + r;
    Xs[r][dd] = (l >= 0) ? xbuf[((size_t)b * 512 + l) * DIN + d0 + dd] : 0.f;
  }
  __syncthreads();
  {
    const int lane = tid & 63, grp = tid >> 6;
    #pragma unroll
    for (int i = 0; i < 16; ++i) {
      int dd = grp + i * 4;
      int d = d0 + dd;
      float acc = cb[d];
      #pragma unroll
      for (int k = 0; k < 4; ++k)
        acc = fmaf(Xs[lane + k][dd], w[d * 4 + k], acc);
      float v = acc / (1.f + __expf(-acc));
      xct[((size_t)b * DIN + d) * LSEQ + l0 + lane] = v;
      Ys[lane][dd] = v;
    }
  }
  __syncthreads();
  {
    const int dd = tid & 63, lg = tid >> 6;
    #pragma unroll
    for (int j = 0; j < 16; ++j) {
      int l = lg * 16 + j;
      bf16 h, lo; bsplit(Ys[l][dd], h, lo);
      size_t o = (size_t)(b * 512 + l0 + l) * DIN + d0 + dd;
      xcAh[o] = h; xcAl[o] = lo;
    }
  }
}

// Selective scan v6: 8 waves/block share one b (and the BC stage); wave -> d;
// lane -> state n. KEY: the per-step cross-lane reduction is gone —
//   ysum = Sum_n a_n + D * Sum_t u[t]*sz[t],  a_n = Sum_t h[t,n]*C[t,n]*sz[t]
// (gate sz[t] is a per-step scalar, so n-reduction commutes with t-sum).
// Per step: 1 ds_read_b64 (B,C) + 3 const-lane readlane broadcasts + 5 math.
// One wave reduction at the very end.
__global__ __launch_bounds__(512) void scan6_k(
    const float* __restrict__ delta_t, const float* __restrict__ xct,
    const float* __restrict__ dbl, const float* __restrict__ zt,
    const float* __restrict__ A_log, const float* __restrict__ Dv,
    float* __restrict__ ysbar)
{
  __shared__ float BC[64][128];      // [t][2n+{0,1}] = {B,C}  32 KB (block-shared)
  const int tid = threadIdx.x;
  const int lane = tid & 63;
  const int wv = tid >> 6;           // 8 waves
  const int bid = blockIdx.x;        // 1536 = 8 * 192
  const int b = bid / 192;
  const int d = (bid - b * 192) * 8 + wv;
  const float Ad2 = -__expf(A_log[d * 64 + lane]) * 1.442695041f;  // exp2 scale
  const float Dd = Dv[d];
  const size_t strm = ((size_t)b * DIN + d) * LSEQ;
  float h = 0.f;
  float a = 0.f;       // Sum_t h[t,n]*C[t,n]*sz[t]   (lane = n)
  float us = 0.f;      // Sum_t u[t]*sz[t]            (lane = t per chunk)

  for (int l0 = 0; l0 < LSEQ; l0 += 64) {
    __syncthreads();
    #pragma unroll
    for (int i = 0; i < 8; ++i) {
      int t = wv * 8 + i;
      const float* src = dbl + (size_t)(b * LSEQ + l0 + t) * 192;
      float2 v; v.x = src[48 + lane]; v.y = src[112 + lane];
      *reinterpret_cast<float2*>(&BC[t][lane * 2]) = v;
    }
    float dt_v = delta_t[strm + l0 + lane];
    float u_v  = xct[strm + l0 + lane];
    float z_v  = zt[strm + l0 + lane];
    float du_v = dt_v * u_v;
    float sz_v = z_v / (1.f + __expf(-z_v));
    us += u_v * sz_v;
    __syncthreads();

    #pragma unroll
    for (int t = 0; t < 64; ++t) {
      float sdt = readlane_f(dt_v, t);
      float sdu = readlane_f(du_v, t);
      float ssz = readlane_f(sz_v, t);
      float2 bc = *reinterpret_cast<const float2*>(&BC[t][lane * 2]);
      float e = exp2f(sdt * Ad2);
      h = fmaf(e, h, sdu * bc.x);
      a = fmaf(h, bc.y * ssz, a);
    }
  }
  float tot = readlane_f(dpp_wave_sum(a + Dd * us), 63);
  if (lane == 0) ysbar[b * 1536 + d] = tot;
}

// out[b][c] = (sum_l fused[b,l,c] + sum_d ysbar[b,d]*W[d,c]) / 512
__global__ __launch_bounds__(256) void final_k(
    const float* __restrict__ fused, const float* __restrict__ ysbar,
    const float* __restrict__ W, float* __restrict__ out)
{
  __shared__ float ys[1536];
  const int b = blockIdx.y;
  const int c = blockIdx.x * 256 + threadIdx.x;
  for (int i = threadIdx.x; i < 1536; i += 256) ys[i] = ysbar[b * 1536 + i];
  __syncthreads();
  float sf = 0.f;
  for (int l = 0; l < 512; ++l) sf += fused[(size_t)((b << 9) + l) * 768 + c];
  float dot = 0.f;
  for (int d = 0; d < 1536; ++d) dot = fmaf(ys[d], W[(size_t)d * 768 + c], dot);
  out[b * 768 + c] = (sf + dot) * (1.f / 512.f);
}

// ---------------------------------------------------------------------------
extern "C" void kernel_launch(void* const* d_in, const int* in_sizes, int n_in,
                              void* d_out, int out_size, void* d_ws, size_t ws_size,
                              hipStream_t stream)
{
  const float* text      = (const float*)d_in[0];
  const float* audio     = (const float*)d_in[1];
  const float* video     = (const float*)d_in[2];
  const float* proj_w    = (const float*)d_in[3];
  const float* proj_b    = (const float*)d_in[4];
  const float* proj_ln_g = (const float*)d_in[5];
  const float* proj_ln_b = (const float*)d_in[6];
  const float* blk_ln_g  = (const float*)d_in[7];
  const float* blk_ln_b  = (const float*)d_in[8];
  const float* in_proj_w = (const float*)d_in[9];
  const float* conv_w    = (const float*)d_in[10];
  const float* conv_b    = (const float*)d_in[11];
  const float* x_proj_w  = (const float*)d_in[12];
  const float* dt_proj_w = (const float*)d_in[13];
  const float* dt_proj_b = (const float*)d_in[14];
  const float* A_log     = (const float*)d_in[15];
  const float* Dv        = (const float*)d_in[16];
  const float* out_projw = (const float*)d_in[17];
  float* out = (float*)d_out;

  // ---- workspace arena ----
  char* p = (char*)d_ws;
  const size_t P768 = (size_t)4096 * 768 * 2;     // one bf16 [4096][768]
  char* S1 = p; p += 6 * P768;                    // modality splits -> hA -> xcA
  char* SW = p; p += 18087936;                    // weights
  char* S3 = p; p += (size_t)4096 * 768 * 4;      // pre
  char* S4 = p; p += (size_t)4096 * 768 * 4;      // fused
  char* S6 = p; p += (size_t)4096 * 1536 * 4;     // xbuf -> delta_t
  char* S7 = p; p += (size_t)4096 * 1536 * 4;     // zt
  char* S8 = p; p += (size_t)4096 * 1536 * 4;     // xct
  char* SD = p; p += (size_t)4096 * 64 * 4;       // dtA hi/lo
  char* S9 = p; p += (size_t)4096 * 192 * 4;      // dbl
  char* SY = p; p += 12288 * 4;                   // ysbar

  bf16* modspl = (bf16*)S1;
  bf16 *tAh = (bf16*)S1,              *tAl = (bf16*)(S1 + P768);
  bf16 *aAh = (bf16*)(S1 + 2 * P768), *aAl = (bf16*)(S1 + 3 * P768);
  bf16 *vAh = (bf16*)(S1 + 4 * P768), *vAl = (bf16*)(S1 + 5 * P768);
  bf16 *hAh = (bf16*)S1,              *hAl = (bf16*)(S1 + P768);
  bf16 *xcAh = (bf16*)S1,             *xcAl = (bf16*)(S1 + (size_t)4096 * 1536 * 2);
  bf16 *pwTh = (bf16*)SW,                    *pwTl = pwTh + (size_t)768 * 2304;
  bf16 *ipTh = pwTl + (size_t)768 * 2304,    *ipTl = ipTh + (size_t)3072 * 768;
  bf16 *xpTh = ipTl + (size_t)3072 * 768,    *xpTl = xpTh + (size_t)192 * 1536;
  bf16 *dtTh = xpTl + (size_t)192 * 1536,    *dtTl = dtTh + (size_t)1536 * 64;
  float* pre     = (float*)S3;
  float* fused   = (float*)S4;
  float* xbuf    = (float*)S6;  float* delta_t = (float*)S6;
  float* zt      = (float*)S7;
  float* xct     = (float*)S8;
  bf16 *dtAh = (bf16*)SD, *dtAl = (bf16*)(SD + (size_t)4096 * 64 * 2);
  float* dbl     = (float*)S9;
  float* ysbar   = (float*)SY;

  // 1) all prep (modality splits + weight transposes) in one launch
  prep_k<<<37968, 256, 0, stream>>>(text, audio, video, modspl,
                                    proj_w, in_proj_w, x_proj_w, dt_proj_w,
                                    pwTh, pwTl, ipTh, ipTl, xpTh, xpTl, dtTh, dtTl);
  // 2) pre = concat @ proj_w + proj_b
  mgemm<128, 64, 4, 2, 1, 1><<<dim3(32, 12), 512, 0, stream>>>(
      tAh, tAl, aAh, aAl, vAh, vAl, pwTh, pwTl, proj_b,
      pre, nullptr, nullptr, nullptr, 2304, 768, 768);
  // 3) fused = LN1(pre); hA = split(LN2(fused))
  ln2_k<<<4096, 256, 0, stream>>>(pre, proj_ln_g, proj_ln_b, blk_ln_g, blk_ln_b, fused, hAh, hAl);
  // 4) [x|z] = h @ in_proj_w: x -> xbuf [4096][1536], z -> zt [B][DIN][L]
  mgemm<128, 128, 2, 2, 0, 5><<<dim3(32, 24), 256, 0, stream>>>(
      hAh, hAl, nullptr, nullptr, nullptr, nullptr, ipTh, ipTl, nullptr,
      xbuf, zt, nullptr, nullptr, 768, 768, 1536);
  // 5) xct = silu(dwconv(x)+cb) transposed; xcA = split(xct) row-major
  conv2x_k<<<dim3(8, 24, 8), 256, 0, stream>>>(xbuf, conv_w, conv_b, xct, xcAh, xcAl);
  // 6) dbl = xconv @ x_proj_w [4096][192] fp32 + dtA hi/lo (cols<48, pad 64)
  mgemm<64, 64, 4, 2, 0, 6><<<dim3(64, 3), 512, 0, stream>>>(
      xcAh, xcAl, nullptr, nullptr, nullptr, nullptr, xpTh, xpTl, nullptr,
      dbl, nullptr, dtAh, dtAl, 1536, 1536, 192);
  // 7) delta_t = softplus(dt @ dt_proj_w + b) transposed [B][DIN][L]
  mgemm<128, 64, 4, 2, 0, 4><<<dim3(32, 24), 512, 0, stream>>>(
      dtAh, dtAl, nullptr, nullptr, nullptr, nullptr, dtTh, dtTl, dt_proj_b,
      delta_t, nullptr, nullptr, nullptr, 64, 64, 0);
  // 8) selective scan -> ysbar[b][d] = sum_l y
  scan6_k<<<1536, 512, 0, stream>>>(delta_t, xct, dbl, zt, A_log, Dv, ysbar);
  // 9) out = (sum_l fused + ysbar @ out_proj_w) / 512
  final_k<<<dim3(3, 8), 256, 0, stream>>>(fused, ysbar, out_projw, out);
}